// Round 3
// baseline (418.961 us; speedup 1.0000x reference)
//
#include <hip/hip_runtime.h>

typedef unsigned short u16;
typedef unsigned int   u32;
typedef unsigned long long u64;

#define HID 128
#define KPB 512      // keys per coarse bucket (shift 9)
#define NBMAX 256    // max coarse buckets (actual: 196)
#define IPB 4096     // incidences per partition workgroup
#define CAP 12288    // LDS val-staging capacity per bucket (mean ~6122)

typedef __bf16 bf16x8 __attribute__((ext_vector_type(8)));
typedef float  f32x4  __attribute__((ext_vector_type(4)));

__device__ inline float u2f(u32 u){ union{u32 u;float f;} v; v.u=u; return v.f; }
__device__ inline u32   f2u(float f){ union{float f;u32 u;} v; v.f=f; return v.u; }
__device__ inline u32  f2bfu(float f){ u32 b=f2u(f); return ((b + 0x7FFFu + ((b>>16)&1u))>>16)&0xFFFFu; }
__device__ inline float blo(u32 u){ return u2f(u<<16); }
__device__ inline float bhi(u32 u){ return u2f(u & 0xFFFF0000u); }

// ---------- fp32 [nN][128] -> bf16 column-quartered table ----------
// quartered layout (u16 units): addr = (q*nN + row)*32 + wc, q = col>>5, wc = col&31
__global__ __launch_bounds__(256) void k_f2bfq(const float* __restrict__ in, u16* __restrict__ out, int nN){
    int id = blockIdx.x*256 + threadIdx.x;   // nN*32 threads, 4 cols each
    if (id >= nN*32) return;
    int row = id >> 5;
    int q   = (id >> 3) & 3;
    int wch = id & 7;
    float4 v = *reinterpret_cast<const float4*>(in + (size_t)row*HID + (id & 31)*4);
    ushort4 o;
    o.x = (u16)f2bfu(v.x); o.y = (u16)f2bfu(v.y);
    o.z = (u16)f2bfu(v.z); o.w = (u16)f2bfu(v.w);
    reinterpret_cast<ushort4*>(out)[((size_t)q*nN + row)*8 + wch] = o;
}

// ---------- W -> MFMA B-fragment-ordered bf16 ----------
__global__ __launch_bounds__(256) void k_wfrag(const float* __restrict__ W, u16* __restrict__ Wf){
    int id = blockIdx.x*256 + threadIdx.x;   // 16384 total
    int i = id & 7, l = (id>>3)&63, j = (id>>9)&7, s = id>>12;
    int k = s*32 + ((l>>4)<<3) + i;
    int n = (j<<4) + (l&15);
    Wf[id] = (u16)f2bfu(W[k*HID + n]);
}

// ---------- coarse histogram over combined key space [0, 2*nN) ----------
__global__ __launch_bounds__(256) void k_hist(const int* __restrict__ nidx, const int* __restrict__ eidx,
                                              int* __restrict__ hist, int nE, int nN, int nb){
    __shared__ int h[NBMAX];
    for (int t=threadIdx.x; t<nb; t+=256) h[t]=0;
    __syncthreads();
    int base = blockIdx.x*IPB;
    for (int k=threadIdx.x; k<IPB; k+=256){
        int j = base+k;
        if (j < nE){
            int n = nidx[j], e = eidx[j];
            atomicAdd(&h[n>>9], 1);
            atomicAdd(&h[(nN+e)>>9], 1);
        }
    }
    __syncthreads();
    for (int t=threadIdx.x; t<nb; t+=256) if (h[t]) atomicAdd(&hist[t], h[t]);
}

// ---------- scan of coarse histogram (1 block); seeds bfill; writes off[nkeys] ----------
__global__ __launch_bounds__(256) void k_bscan(const int* __restrict__ hist, int* __restrict__ bbase,
                                               int* __restrict__ bfill, int* __restrict__ off,
                                               int nb, int nkeys, int total){
    __shared__ int sd[256];
    int t = threadIdx.x;
    int v = (t < nb) ? hist[t] : 0;
    sd[t] = v; __syncthreads();
    for (int o=1;o<256;o<<=1){ int u = (t>=o)? sd[t-o] : 0; __syncthreads(); sd[t]+=u; __syncthreads(); }
    int ex = sd[t] - v;
    if (t < nb){ bbase[t] = ex; bfill[t] = ex; }
    if (t == 0){ bbase[nb] = total; off[nkeys] = total; }
}

// ---------- partition into coarse buckets: (key,val) u64 pairs ----------
__global__ __launch_bounds__(256) void k_part(const int* __restrict__ nidx, const int* __restrict__ eidx,
                                              int* __restrict__ bfill, u64* __restrict__ pairs,
                                              int nE, int nN, int nb){
    __shared__ int h[NBMAX], rsv[NBMAX], fl[NBMAX];
    for (int t=threadIdx.x; t<nb; t+=256){ h[t]=0; fl[t]=0; }
    __syncthreads();
    int base = blockIdx.x*IPB;
    for (int k=threadIdx.x; k<IPB; k+=256){
        int j = base+k;
        if (j < nE){
            int n = nidx[j], e = eidx[j];
            atomicAdd(&h[n>>9], 1);
            atomicAdd(&h[(nN+e)>>9], 1);
        }
    }
    __syncthreads();
    for (int t=threadIdx.x; t<nb; t+=256){ if (h[t]) rsv[t] = atomicAdd(&bfill[t], h[t]); }
    __syncthreads();
    for (int k=threadIdx.x; k<IPB; k+=256){
        int j = base+k;
        if (j < nE){
            int n = nidx[j], e = eidx[j];
            int b1 = n>>9;
            int p1 = rsv[b1] + atomicAdd(&fl[b1], 1);
            pairs[p1] = ((u64)(u32)n << 32) | (u32)e;
            int k2 = nN + e;
            int b2 = k2>>9;
            int p2 = rsv[b2] + atomicAdd(&fl[b2], 1);
            pairs[p2] = ((u64)(u32)k2 << 32) | (u32)n;
        }
    }
}

// ---------- per-bucket fine counting sort in LDS: csr (coalesced) + off ----------
__global__ __launch_bounds__(256) void k_bucket(const u64* __restrict__ pairs, const int* __restrict__ bbase,
                                                int* __restrict__ csr, int* __restrict__ off, int nkeys){
    __shared__ int cntS[KPB];
    __shared__ int fillS[KPB];
    __shared__ int sd[256];
    __shared__ int vals[CAP];
    int b = blockIdx.x;
    int t = threadIdx.x;
    int base = bbase[b];
    int n = bbase[b+1] - base;
    int k0 = b * KPB;

    for (int i=t; i<KPB; i+=256) cntS[i] = 0;
    __syncthreads();
    for (int i=t; i<n; i+=256){
        u64 p = pairs[base+i];
        int kl = (int)(p>>32) - k0;
        atomicAdd(&cntS[kl], 1);
    }
    __syncthreads();
    int c0 = cntS[2*t], c1 = cntS[2*t+1];
    int s = c0 + c1;
    sd[t] = s; __syncthreads();
    for (int o=1;o<256;o<<=1){ int u = (t>=o)? sd[t-o] : 0; __syncthreads(); sd[t]+=u; __syncthreads(); }
    int ex = sd[t] - s;
    __syncthreads();
    cntS[2*t]   = ex;        cntS[2*t+1]   = ex + c0;
    fillS[2*t]  = ex;        fillS[2*t+1]  = ex + c0;
    __syncthreads();
    for (int i=t; i<KPB; i+=256){
        int k = k0 + i;
        if (k < nkeys) off[k] = base + cntS[i];
    }
    bool fits = (n <= CAP);
    for (int i=t; i<n; i+=256){
        u64 p = pairs[base+i];
        int kl = (int)(p>>32) - k0;
        int pos = atomicAdd(&fillS[kl], 1);
        if (fits) vals[pos] = (int)(u32)p;
        else      csr[base+pos] = (int)(u32)p;
    }
    __syncthreads();
    if (fits){
        for (int i=t; i<n; i+=256) csr[base+i] = vals[i];
    }
}

// ---------- MFMA GEMM: C = A @ W, A/C in column-quartered bf16 layout ----------
__global__ __launch_bounds__(256) void k_gemm(const u16* __restrict__ A, const u16* __restrict__ Wf,
                                              u16* __restrict__ C, int M){
    int wave = blockIdx.x*4 + (threadIdx.x>>6);
    int lane = threadIdx.x & 63;
    int rtiles = M >> 4;
    if (wave >= rtiles) return;
    int row0 = wave << 4;

    int arow = row0 + (lane&15);
    int aoff = (lane>>4)<<3;
    const bf16x8* Wp = reinterpret_cast<const bf16x8*>(Wf) + lane;

    f32x4 acc[8];
    #pragma unroll
    for (int j=0;j<8;++j) acc[j] = (f32x4){0.f,0.f,0.f,0.f};

    #pragma unroll
    for (int s=0;s<4;++s){
        // A quartered: quarter s holds K-cols [32s, 32s+32)
        bf16x8 a = *reinterpret_cast<const bf16x8*>(A + ((size_t)s*M + arow)*32 + aoff);
        #pragma unroll
        for (int j=0;j<8;++j){
            bf16x8 b = Wp[(s*8 + j)*64];
            acc[j] = __builtin_amdgcn_mfma_f32_16x16x32_bf16(a, b, acc[j], 0, 0, 0);
        }
    }
    int r0 = row0 + ((lane>>4)<<2);
    int c0 = lane & 15;
    #pragma unroll
    for (int j=0;j<8;++j){
        int col = j*16 + c0;
        int q = col >> 5, wc = col & 31;
        #pragma unroll
        for (int r=0;r<4;++r){
            C[((size_t)q*M + r0 + r)*32 + wc] = (u16)f2bfu(acc[j][r]);
        }
    }
}

// ---------- quartered CSR-gather segment mean ----------
// one wave per (dest row, quarter); 16 lanes per source row -> 4 rows/iter, x2 unroll
// MODE 0: out bf16 quartered, scale only
// MODE 1: out bf16 quartered, scale + bias + prelu
// MODE 2: out fp32 row-major d_out, scale + bias + residual + prelu
template<int MODE>
__global__ __launch_bounds__(256) void k_agg(const u32* __restrict__ tab, const int* __restrict__ csr,
                                             const int* __restrict__ off, void* __restrict__ outp,
                                             const float* __restrict__ bias, const float* __restrict__ resid,
                                             const float* __restrict__ aptr, int nN, int nblkq){
    int q   = blockIdx.x / nblkq;            // quarter: slow-varying -> temporal phases
    int blk = blockIdx.x - q*nblkq;
    int d = blk*4 + (threadIdx.x>>6);
    if (d >= nN) return;
    int lane = threadIdx.x & 63;
    int g = lane >> 4;        // source-row group 0..3
    int c = lane & 15;        // col-pair index within quarter
    int start = off[d], end = off[d+1];
    const u32* tq = tab + (size_t)q*nN*16;

    float a0 = 0.f, a1 = 0.f;
    for (int j = start; j < end; j += 8){
        int r0 = j + g, r1 = r0 + 4;
        int s0 = (r0 < end) ? csr[r0] : -1;
        int s1 = (r1 < end) ? csr[r1] : -1;
        u32 u0 = (s0 >= 0) ? tq[(size_t)s0*16 + c] : 0u;
        u32 u1 = (s1 >= 0) ? tq[(size_t)s1*16 + c] : 0u;
        a0 += blo(u0) + blo(u1);
        a1 += bhi(u0) + bhi(u1);
    }
    a0 += __shfl_xor(a0, 32, 64);  a1 += __shfl_xor(a1, 32, 64);
    a0 += __shfl_xor(a0, 16, 64);  a1 += __shfl_xor(a1, 16, 64);

    float scale = (end > start) ? 1.0f/(float)(end-start) : 0.f;
    a0 *= scale; a1 *= scale;
    if constexpr (MODE >= 1){ a0 += bias[32*q + 2*c]; a1 += bias[32*q + 2*c + 1]; }
    if constexpr (MODE == 2){
        float2 xr = reinterpret_cast<const float2*>(resid)[(size_t)d*64 + q*16 + c];
        a0 += xr.x; a1 += xr.y;
    }
    if constexpr (MODE >= 1){
        float al = aptr[0];
        a0 = (a0 >= 0.f) ? a0 : al*a0;
        a1 = (a1 >= 0.f) ? a1 : al*a1;
    }
    if (g == 0){
        if constexpr (MODE == 2){
            reinterpret_cast<float2*>(outp)[(size_t)d*64 + q*16 + c] = make_float2(a0, a1);
        } else {
            reinterpret_cast<u32*>(outp)[((size_t)q*nN + d)*16 + c] = (f2bfu(a1)<<16) | f2bfu(a0);
        }
    }
}

extern "C" void kernel_launch(void* const* d_in, const int* in_sizes, int n_in,
                              void* d_out, int out_size, void* d_ws, size_t ws_size,
                              hipStream_t stream){
    (void)n_in; (void)out_size; (void)ws_size;
    const float* x  = (const float*)d_in[0];
    const int*  hei = (const int*)  d_in[1];
    const float* W1 = (const float*)d_in[2];
    const float* b1 = (const float*)d_in[3];
    const float* W2 = (const float*)d_in[4];
    const float* b2 = (const float*)d_in[5];
    const float* ap = (const float*)d_in[6];

    const int nN = in_sizes[0] / HID;   // 50000
    const int nE = in_sizes[1] / 2;     // 600000
    const int* nidx = hei;
    const int* eidx = hei + nE;
    const int nkeys = 2*nN;
    const int nb    = (nkeys + KPB - 1) / KPB;   // 196

    char* w = (char*)d_ws;
    size_t o = 0;
    auto alloc = [&](size_t bytes)->void*{
        void* p = (void*)(w + o);
        o += (bytes + 255) & ~(size_t)255;
        return p;
    };
    int* hist  = (int*)alloc((size_t)NBMAX*sizeof(int));
    int* bbase = (int*)alloc((size_t)(NBMAX+1)*sizeof(int));
    int* bfill = (int*)alloc((size_t)NBMAX*sizeof(int));
    int* off   = (int*)alloc(((size_t)nkeys+1)*sizeof(int));
    int* csr   = (int*)alloc((size_t)2*nE*sizeof(int));
    u64* pairs = (u64*)alloc((size_t)2*nE*sizeof(u64));
    u16* xb    = (u16*)alloc((size_t)nN*HID*sizeof(u16));   // x bf16 quartered; reused as h
    u16* bufB  = (u16*)alloc((size_t)nN*HID*sizeof(u16));   // xw / hw quartered
    u16* bufC  = (u16*)alloc((size_t)nN*HID*sizeof(u16));   // m / m2 quartered
    u16* w1f   = (u16*)alloc((size_t)HID*HID*sizeof(u16));
    u16* w2f   = (u16*)alloc((size_t)HID*HID*sizeof(u16));

    hipMemsetAsync(hist, 0, (size_t)nb*sizeof(int), stream);

    k_f2bfq<<<(nN*32+255)/256, 256, 0, stream>>>(x, xb, nN);
    k_wfrag<<<64, 256, 0, stream>>>(W1, w1f);
    k_wfrag<<<64, 256, 0, stream>>>(W2, w2f);

    const int pgrid = (nE + IPB - 1)/IPB;       // 147
    k_hist <<<pgrid, 256, 0, stream>>>(nidx, eidx, hist, nE, nN, nb);
    k_bscan<<<1,     256, 0, stream>>>(hist, bbase, bfill, off, nb, nkeys, 2*nE);
    k_part <<<pgrid, 256, 0, stream>>>(nidx, eidx, bfill, pairs, nE, nN, nb);
    k_bucket<<<nb,   256, 0, stream>>>(pairs, bbase, csr, off, nkeys);

    const int rtiles = nN/16;
    const int ggrid  = (rtiles + 3)/4;
    const int nblkq  = (nN + 3)/4;              // 12500
    const int agrid  = nblkq*4;                 // 50000 blocks, quarter-phased

    // layer 1
    k_gemm<<<ggrid, 256, 0, stream>>>(xb, w1f, bufB, nN);
    k_agg<0><<<agrid, 256, 0, stream>>>((const u32*)bufB, csr, off + nN, bufC, nullptr, nullptr, nullptr, nN, nblkq);
    k_agg<1><<<agrid, 256, 0, stream>>>((const u32*)bufC, csr, off,      xb,   b1, nullptr, ap, nN, nblkq);
    // layer 2
    k_gemm<<<ggrid, 256, 0, stream>>>(xb, w2f, bufB, nN);
    k_agg<0><<<agrid, 256, 0, stream>>>((const u32*)bufB, csr, off + nN, bufC, nullptr, nullptr, nullptr, nN, nblkq);
    k_agg<2><<<agrid, 256, 0, stream>>>((const u32*)bufC, csr, off, d_out, b2, x, ap, nN, nblkq);
}

// Round 4
// 258.669 us; speedup vs baseline: 1.6197x; 1.6197x over previous
//
#include <hip/hip_runtime.h>

typedef unsigned short u16;
typedef unsigned int   u32;
typedef unsigned long long u64;

#define HID 128
#define KPB 512      // keys per coarse bucket (shift 9)
#define NBMAX 256    // max coarse buckets (actual: 196)
#define IPB 4096     // incidences per partition workgroup
#define CAP 12288    // LDS val-staging capacity per bucket (mean ~6122)

typedef __bf16 bf16x8 __attribute__((ext_vector_type(8)));
typedef float  f32x4  __attribute__((ext_vector_type(4)));

__device__ inline float u2f(u32 u){ union{u32 u;float f;} v; v.u=u; return v.f; }
__device__ inline u32   f2u(float f){ union{float f;u32 u;} v; v.f=f; return v.u; }
__device__ inline u32  f2bfu(float f){ u32 b=f2u(f); return ((b + 0x7FFFu + ((b>>16)&1u))>>16)&0xFFFFu; }
__device__ inline float blo(u32 u){ return u2f(u<<16); }
__device__ inline float bhi(u32 u){ return u2f(u & 0xFFFF0000u); }
__device__ inline u32  pk(float lo, float hi){ return (f2bfu(hi)<<16) | f2bfu(lo); }

// ---------- fp32 -> bf16 table conversion (row-major) ----------
__global__ __launch_bounds__(256) void k_f2bf4(const float4* __restrict__ in, ushort4* __restrict__ out, int n4){
    int i = blockIdx.x*256 + threadIdx.x;
    if (i < n4){
        float4 v = in[i];
        ushort4 o;
        o.x = (u16)f2bfu(v.x); o.y = (u16)f2bfu(v.y);
        o.z = (u16)f2bfu(v.z); o.w = (u16)f2bfu(v.w);
        out[i] = o;
    }
}

// ---------- W -> MFMA B-fragment-ordered bf16 ----------
__global__ __launch_bounds__(256) void k_wfrag(const float* __restrict__ W, u16* __restrict__ Wf){
    int id = blockIdx.x*256 + threadIdx.x;   // 16384 total
    int i = id & 7, l = (id>>3)&63, j = (id>>9)&7, s = id>>12;
    int k = s*32 + ((l>>4)<<3) + i;
    int n = (j<<4) + (l&15);
    Wf[id] = (u16)f2bfu(W[k*HID + n]);
}

// ---------- coarse histogram over combined key space [0, 2*nN) ----------
__global__ __launch_bounds__(256) void k_hist(const int* __restrict__ nidx, const int* __restrict__ eidx,
                                              int* __restrict__ hist, int nE, int nN, int nb){
    __shared__ int h[NBMAX];
    for (int t=threadIdx.x; t<nb; t+=256) h[t]=0;
    __syncthreads();
    int base = blockIdx.x*IPB;
    for (int k=threadIdx.x; k<IPB; k+=256){
        int j = base+k;
        if (j < nE){
            int n = nidx[j], e = eidx[j];
            atomicAdd(&h[n>>9], 1);
            atomicAdd(&h[(nN+e)>>9], 1);
        }
    }
    __syncthreads();
    for (int t=threadIdx.x; t<nb; t+=256) if (h[t]) atomicAdd(&hist[t], h[t]);
}

// ---------- scan of coarse histogram (1 block); seeds bfill; writes off[nkeys] ----------
__global__ __launch_bounds__(256) void k_bscan(const int* __restrict__ hist, int* __restrict__ bbase,
                                               int* __restrict__ bfill, int* __restrict__ off,
                                               int nb, int nkeys, int total){
    __shared__ int sd[256];
    int t = threadIdx.x;
    int v = (t < nb) ? hist[t] : 0;
    sd[t] = v; __syncthreads();
    for (int o=1;o<256;o<<=1){ int u = (t>=o)? sd[t-o] : 0; __syncthreads(); sd[t]+=u; __syncthreads(); }
    int ex = sd[t] - v;
    if (t < nb){ bbase[t] = ex; bfill[t] = ex; }
    if (t == 0){ bbase[nb] = total; off[nkeys] = total; }
}

// ---------- partition into coarse buckets: (key,val) u64 pairs ----------
__global__ __launch_bounds__(256) void k_part(const int* __restrict__ nidx, const int* __restrict__ eidx,
                                              int* __restrict__ bfill, u64* __restrict__ pairs,
                                              int nE, int nN, int nb){
    __shared__ int h[NBMAX], rsv[NBMAX], fl[NBMAX];
    for (int t=threadIdx.x; t<nb; t+=256){ h[t]=0; fl[t]=0; }
    __syncthreads();
    int base = blockIdx.x*IPB;
    for (int k=threadIdx.x; k<IPB; k+=256){
        int j = base+k;
        if (j < nE){
            int n = nidx[j], e = eidx[j];
            atomicAdd(&h[n>>9], 1);
            atomicAdd(&h[(nN+e)>>9], 1);
        }
    }
    __syncthreads();
    for (int t=threadIdx.x; t<nb; t+=256){ if (h[t]) rsv[t] = atomicAdd(&bfill[t], h[t]); }
    __syncthreads();
    for (int k=threadIdx.x; k<IPB; k+=256){
        int j = base+k;
        if (j < nE){
            int n = nidx[j], e = eidx[j];
            int b1 = n>>9;
            int p1 = rsv[b1] + atomicAdd(&fl[b1], 1);
            pairs[p1] = ((u64)(u32)n << 32) | (u32)e;
            int k2 = nN + e;
            int b2 = k2>>9;
            int p2 = rsv[b2] + atomicAdd(&fl[b2], 1);
            pairs[p2] = ((u64)(u32)k2 << 32) | (u32)n;
        }
    }
}

// ---------- per-bucket fine counting sort in LDS: csr (coalesced) + off ----------
__global__ __launch_bounds__(256) void k_bucket(const u64* __restrict__ pairs, const int* __restrict__ bbase,
                                                int* __restrict__ csr, int* __restrict__ off, int nkeys){
    __shared__ int cntS[KPB];
    __shared__ int fillS[KPB];
    __shared__ int sd[256];
    __shared__ int vals[CAP];
    int b = blockIdx.x;
    int t = threadIdx.x;
    int base = bbase[b];
    int n = bbase[b+1] - base;
    int k0 = b * KPB;

    for (int i=t; i<KPB; i+=256) cntS[i] = 0;
    __syncthreads();
    for (int i=t; i<n; i+=256){
        u64 p = pairs[base+i];
        int kl = (int)(p>>32) - k0;
        atomicAdd(&cntS[kl], 1);
    }
    __syncthreads();
    int c0 = cntS[2*t], c1 = cntS[2*t+1];
    int s = c0 + c1;
    sd[t] = s; __syncthreads();
    for (int o=1;o<256;o<<=1){ int u = (t>=o)? sd[t-o] : 0; __syncthreads(); sd[t]+=u; __syncthreads(); }
    int ex = sd[t] - s;
    __syncthreads();
    cntS[2*t]   = ex;        cntS[2*t+1]   = ex + c0;
    fillS[2*t]  = ex;        fillS[2*t+1]  = ex + c0;
    __syncthreads();
    for (int i=t; i<KPB; i+=256){
        int k = k0 + i;
        if (k < nkeys) off[k] = base + cntS[i];
    }
    bool fits = (n <= CAP);
    for (int i=t; i<n; i+=256){
        u64 p = pairs[base+i];
        int kl = (int)(p>>32) - k0;
        int pos = atomicAdd(&fillS[kl], 1);
        if (fits) vals[pos] = (int)(u32)p;
        else      csr[base+pos] = (int)(u32)p;
    }
    __syncthreads();
    if (fits){
        for (int i=t; i<n; i+=256) csr[base+i] = vals[i];
    }
}

// ---------- MFMA GEMM: C[M x 128] = A[M x 128] @ W[128 x 128], bf16 in/out, row-major ----------
__global__ __launch_bounds__(256) void k_gemm(const u16* __restrict__ A, const u16* __restrict__ Wf,
                                              u16* __restrict__ C, int M){
    int wave = blockIdx.x*4 + (threadIdx.x>>6);
    int lane = threadIdx.x & 63;
    int rtiles = M >> 4;
    if (wave >= rtiles) return;
    int row0 = wave << 4;

    const u16* Arow = A + (size_t)(row0 + (lane&15))*HID + ((lane>>4)<<3);
    const bf16x8* Wp = reinterpret_cast<const bf16x8*>(Wf) + lane;

    f32x4 acc[8];
    #pragma unroll
    for (int j=0;j<8;++j) acc[j] = (f32x4){0.f,0.f,0.f,0.f};

    #pragma unroll
    for (int s=0;s<4;++s){
        bf16x8 a = *reinterpret_cast<const bf16x8*>(Arow + s*32);
        #pragma unroll
        for (int j=0;j<8;++j){
            bf16x8 b = Wp[(s*8 + j)*64];
            acc[j] = __builtin_amdgcn_mfma_f32_16x16x32_bf16(a, b, acc[j], 0, 0, 0);
        }
    }
    int r0 = row0 + ((lane>>4)<<2);
    int c0 = lane & 15;
    #pragma unroll
    for (int j=0;j<8;++j){
        #pragma unroll
        for (int r=0;r<4;++r){
            C[(size_t)(r0+r)*HID + j*16 + c0] = (u16)f2bfu(acc[j][r]);
        }
    }
}

// ---------- CSR-gather segment mean, dwordx4 ----------
// one wave per dest row; 4 groups x 16 lanes; group g loads source row j+g,
// lane chunk c covers cols [8c, 8c+8) as 4 u32 (16B dwordx4).
// MODE 0: out bf16 row-major, scale only
// MODE 1: out bf16 row-major, scale + bias + prelu
// MODE 2: out fp32 row-major, scale + bias + residual + prelu
template<int MODE>
__global__ __launch_bounds__(256) void k_agg(const u32* __restrict__ tab, const int* __restrict__ csr,
                                             const int* __restrict__ off, void* __restrict__ outp,
                                             const float* __restrict__ bias, const float* __restrict__ resid,
                                             const float* __restrict__ aptr, int nrows){
    int d = blockIdx.x*4 + (threadIdx.x>>6);
    if (d >= nrows) return;
    int lane = threadIdx.x & 63;
    int g = lane >> 4;
    int c = lane & 15;
    int start = off[d], end = off[d+1];
    int deg = end - start;

    // prefetch csr window into lane registers (covers deg <= 64; tail loop below)
    int myc = 0;
    if (lane < deg) myc = csr[start + lane];

    float a0=0.f,a1=0.f,a2=0.f,a3=0.f,a4=0.f,a5=0.f,a6=0.f,a7=0.f;
    int nb4 = deg < 64 ? deg : 64;
    for (int jb = 0; jb < nb4; jb += 4){
        int j = jb + g;
        int src = __shfl(myc, j, 64);
        uint4 v = make_uint4(0u,0u,0u,0u);
        if (j < nb4) v = *reinterpret_cast<const uint4*>(tab + (size_t)src*64 + (c<<2));
        a0 += blo(v.x); a1 += bhi(v.x);
        a2 += blo(v.y); a3 += bhi(v.y);
        a4 += blo(v.z); a5 += bhi(v.z);
        a6 += blo(v.w); a7 += bhi(v.w);
    }
    // statistically-rare tail: deg > 64
    for (int j = start + 64; j < end; ++j){
        uint4 v = make_uint4(0u,0u,0u,0u);
        if (g == 0){
            int src = csr[j];
            v = *reinterpret_cast<const uint4*>(tab + (size_t)src*64 + (c<<2));
        }
        a0 += blo(v.x); a1 += bhi(v.x);
        a2 += blo(v.y); a3 += bhi(v.y);
        a4 += blo(v.z); a5 += bhi(v.z);
        a6 += blo(v.w); a7 += bhi(v.w);
    }
    // cross-group reduction (result valid in all lanes; only g==0 uses it)
    a0 += __shfl_xor(a0,16,64); a0 += __shfl_xor(a0,32,64);
    a1 += __shfl_xor(a1,16,64); a1 += __shfl_xor(a1,32,64);
    a2 += __shfl_xor(a2,16,64); a2 += __shfl_xor(a2,32,64);
    a3 += __shfl_xor(a3,16,64); a3 += __shfl_xor(a3,32,64);
    a4 += __shfl_xor(a4,16,64); a4 += __shfl_xor(a4,32,64);
    a5 += __shfl_xor(a5,16,64); a5 += __shfl_xor(a5,32,64);
    a6 += __shfl_xor(a6,16,64); a6 += __shfl_xor(a6,32,64);
    a7 += __shfl_xor(a7,16,64); a7 += __shfl_xor(a7,32,64);

    if (g == 0){
        float s = (deg > 0) ? 1.0f/(float)deg : 0.f;
        a0*=s; a1*=s; a2*=s; a3*=s; a4*=s; a5*=s; a6*=s; a7*=s;
        if constexpr (MODE >= 1){
            float4 b0 = *reinterpret_cast<const float4*>(bias + (c<<3));
            float4 b1v = *reinterpret_cast<const float4*>(bias + (c<<3) + 4);
            a0+=b0.x; a1+=b0.y; a2+=b0.z; a3+=b0.w;
            a4+=b1v.x; a5+=b1v.y; a6+=b1v.z; a7+=b1v.w;
        }
        if constexpr (MODE == 2){
            const float* rp = resid + (size_t)d*HID + (c<<3);
            float4 r0 = *reinterpret_cast<const float4*>(rp);
            float4 r1 = *reinterpret_cast<const float4*>(rp + 4);
            a0+=r0.x; a1+=r0.y; a2+=r0.z; a3+=r0.w;
            a4+=r1.x; a5+=r1.y; a6+=r1.z; a7+=r1.w;
        }
        if constexpr (MODE >= 1){
            float al = aptr[0];
            a0 = (a0>=0.f)? a0 : al*a0;  a1 = (a1>=0.f)? a1 : al*a1;
            a2 = (a2>=0.f)? a2 : al*a2;  a3 = (a3>=0.f)? a3 : al*a3;
            a4 = (a4>=0.f)? a4 : al*a4;  a5 = (a5>=0.f)? a5 : al*a5;
            a6 = (a6>=0.f)? a6 : al*a6;  a7 = (a7>=0.f)? a7 : al*a7;
        }
        if constexpr (MODE == 2){
            float* op = (float*)outp + (size_t)d*HID + (c<<3);
            *reinterpret_cast<float4*>(op)     = make_float4(a0,a1,a2,a3);
            *reinterpret_cast<float4*>(op + 4) = make_float4(a4,a5,a6,a7);
        } else {
            uint4 wv;
            wv.x = pk(a0,a1); wv.y = pk(a2,a3); wv.z = pk(a4,a5); wv.w = pk(a6,a7);
            *reinterpret_cast<uint4*>((u32*)outp + (size_t)d*64 + (c<<2)) = wv;
        }
    }
}

extern "C" void kernel_launch(void* const* d_in, const int* in_sizes, int n_in,
                              void* d_out, int out_size, void* d_ws, size_t ws_size,
                              hipStream_t stream){
    (void)n_in; (void)out_size; (void)ws_size;
    const float* x  = (const float*)d_in[0];
    const int*  hei = (const int*)  d_in[1];
    const float* W1 = (const float*)d_in[2];
    const float* b1 = (const float*)d_in[3];
    const float* W2 = (const float*)d_in[4];
    const float* b2 = (const float*)d_in[5];
    const float* ap = (const float*)d_in[6];

    const int nN = in_sizes[0] / HID;   // 50000
    const int nE = in_sizes[1] / 2;     // 600000
    const int* nidx = hei;
    const int* eidx = hei + nE;
    const int nkeys = 2*nN;
    const int nb    = (nkeys + KPB - 1) / KPB;   // 196

    char* w = (char*)d_ws;
    size_t o = 0;
    auto alloc = [&](size_t bytes)->void*{
        void* p = (void*)(w + o);
        o += (bytes + 255) & ~(size_t)255;
        return p;
    };
    int* hist  = (int*)alloc((size_t)NBMAX*sizeof(int));
    int* bbase = (int*)alloc((size_t)(NBMAX+1)*sizeof(int));
    int* bfill = (int*)alloc((size_t)NBMAX*sizeof(int));
    int* off   = (int*)alloc(((size_t)nkeys+1)*sizeof(int));
    int* csr   = (int*)alloc((size_t)2*nE*sizeof(int));
    u64* pairs = (u64*)alloc((size_t)2*nE*sizeof(u64));
    u16* xb    = (u16*)alloc((size_t)nN*HID*sizeof(u16));   // x bf16; reused as h bf16
    u16* bufB  = (u16*)alloc((size_t)nN*HID*sizeof(u16));   // xw / hw
    u16* bufC  = (u16*)alloc((size_t)nN*HID*sizeof(u16));   // m / m2
    u16* w1f   = (u16*)alloc((size_t)HID*HID*sizeof(u16));
    u16* w2f   = (u16*)alloc((size_t)HID*HID*sizeof(u16));

    hipMemsetAsync(hist, 0, (size_t)nb*sizeof(int), stream);

    const int n4 = nN*HID/4;
    k_f2bf4<<<(n4+255)/256, 256, 0, stream>>>((const float4*)x, (ushort4*)xb, n4);
    k_wfrag<<<64, 256, 0, stream>>>(W1, w1f);
    k_wfrag<<<64, 256, 0, stream>>>(W2, w2f);

    const int pgrid = (nE + IPB - 1)/IPB;       // 147
    k_hist <<<pgrid, 256, 0, stream>>>(nidx, eidx, hist, nE, nN, nb);
    k_bscan<<<1,     256, 0, stream>>>(hist, bbase, bfill, off, nb, nkeys, 2*nE);
    k_part <<<pgrid, 256, 0, stream>>>(nidx, eidx, bfill, pairs, nE, nN, nb);
    k_bucket<<<nb,   256, 0, stream>>>(pairs, bbase, csr, off, nkeys);

    const int rtiles = nN/16;
    const int ggrid  = (rtiles + 3)/4;
    const int agrid  = (nN + 3)/4;

    // layer 1
    k_gemm<<<ggrid, 256, 0, stream>>>(xb, w1f, bufB, nN);
    k_agg<0><<<agrid, 256, 0, stream>>>((const u32*)bufB, csr, off + nN, bufC, nullptr, nullptr, nullptr, nN);
    k_agg<1><<<agrid, 256, 0, stream>>>((const u32*)bufC, csr, off,      xb,   b1, nullptr, ap, nN);
    // layer 2
    k_gemm<<<ggrid, 256, 0, stream>>>(xb, w2f, bufB, nN);
    k_agg<0><<<agrid, 256, 0, stream>>>((const u32*)bufB, csr, off + nN, bufC, nullptr, nullptr, nullptr, nN);
    k_agg<2><<<agrid, 256, 0, stream>>>((const u32*)bufC, csr, off, d_out, b2, x, ap, nN);
}

// Round 5
// 253.161 us; speedup vs baseline: 1.6549x; 1.0218x over previous
//
#include <hip/hip_runtime.h>

typedef unsigned short u16;
typedef unsigned int   u32;
typedef unsigned long long u64;

#define HID 128
#define KPB 256      // keys per coarse bucket (shift 8)
#define NBMAX 512    // max coarse buckets (actual: 391)
#define IPB 2048     // incidences per partition workgroup
#define CAP 6144     // LDS val-staging capacity per bucket (mean ~3070, sd ~55)

typedef __bf16 bf16x8 __attribute__((ext_vector_type(8)));
typedef float  f32x4  __attribute__((ext_vector_type(4)));

__device__ inline float u2f(u32 u){ union{u32 u;float f;} v; v.u=u; return v.f; }
__device__ inline u32   f2u(float f){ union{float f;u32 u;} v; v.f=f; return v.u; }
__device__ inline u32  f2bfu(float f){ u32 b=f2u(f); return ((b + 0x7FFFu + ((b>>16)&1u))>>16)&0xFFFFu; }
__device__ inline float blo(u32 u){ return u2f(u<<16); }
__device__ inline float bhi(u32 u){ return u2f(u & 0xFFFF0000u); }
__device__ inline u32  pk(float lo, float hi){ return (f2bfu(hi)<<16) | f2bfu(lo); }

// ---------- W1,W2 -> MFMA B-fragment-ordered bf16 (one launch) ----------
// Wf linear index (((s*8 + j)*64) + lane)*8 + i holds W[k][n], k=s*32+(lane>>4)*8+i, n=j*16+(lane&15)
__global__ __launch_bounds__(256) void k_wfrag2(const float* __restrict__ W1, const float* __restrict__ W2,
                                                u16* __restrict__ W1f, u16* __restrict__ W2f){
    int gid = blockIdx.x*256 + threadIdx.x;   // 32768 total
    const float* W = (gid < 16384) ? W1 : W2;
    u16* Wf = (gid < 16384) ? W1f : W2f;
    int id = gid & 16383;
    int i = id & 7, l = (id>>3)&63, j = (id>>9)&7, s = id>>12;
    int k = s*32 + ((l>>4)<<3) + i;
    int n = (j<<4) + (l&15);
    Wf[id] = (u16)f2bfu(W[k*HID + n]);
}

// ---------- coarse histogram over combined key space [0, 2*nN) ----------
__global__ __launch_bounds__(256) void k_hist(const int* __restrict__ nidx, const int* __restrict__ eidx,
                                              int* __restrict__ hist, int nE, int nN, int nb){
    __shared__ int h[NBMAX];
    for (int t=threadIdx.x; t<nb; t+=256) h[t]=0;
    __syncthreads();
    int base = blockIdx.x*IPB;
    for (int k=threadIdx.x; k<IPB; k+=256){
        int j = base+k;
        if (j < nE){
            int n = nidx[j], e = eidx[j];
            atomicAdd(&h[n>>8], 1);
            atomicAdd(&h[(nN+e)>>8], 1);
        }
    }
    __syncthreads();
    for (int t=threadIdx.x; t<nb; t+=256) if (h[t]) atomicAdd(&hist[t], h[t]);
}

// ---------- scan of coarse histogram (1 block, 2 elems/thread); seeds bfill; off[nkeys] ----------
__global__ __launch_bounds__(256) void k_bscan(const int* __restrict__ hist, int* __restrict__ bbase,
                                               int* __restrict__ bfill, int* __restrict__ off,
                                               int nb, int nkeys, int total){
    __shared__ int sd[256];
    int t = threadIdx.x;
    int c0 = (2*t   < nb) ? hist[2*t]   : 0;
    int c1 = (2*t+1 < nb) ? hist[2*t+1] : 0;
    int s = c0 + c1;
    sd[t] = s; __syncthreads();
    for (int o=1;o<256;o<<=1){ int u = (t>=o)? sd[t-o] : 0; __syncthreads(); sd[t]+=u; __syncthreads(); }
    int ex = sd[t] - s;
    if (2*t   < nb){ bbase[2*t]   = ex;      bfill[2*t]   = ex; }
    if (2*t+1 < nb){ bbase[2*t+1] = ex+c0;   bfill[2*t+1] = ex+c0; }
    if (t == 0){ bbase[nb] = total; off[nkeys] = total; }
}

// ---------- partition into coarse buckets: (key,val) u64 pairs ----------
__global__ __launch_bounds__(256) void k_part(const int* __restrict__ nidx, const int* __restrict__ eidx,
                                              int* __restrict__ bfill, u64* __restrict__ pairs,
                                              int nE, int nN, int nb){
    __shared__ int h[NBMAX], rsv[NBMAX], fl[NBMAX];
    for (int t=threadIdx.x; t<nb; t+=256){ h[t]=0; fl[t]=0; }
    __syncthreads();
    int base = blockIdx.x*IPB;
    for (int k=threadIdx.x; k<IPB; k+=256){
        int j = base+k;
        if (j < nE){
            int n = nidx[j], e = eidx[j];
            atomicAdd(&h[n>>8], 1);
            atomicAdd(&h[(nN+e)>>8], 1);
        }
    }
    __syncthreads();
    for (int t=threadIdx.x; t<nb; t+=256){ if (h[t]) rsv[t] = atomicAdd(&bfill[t], h[t]); }
    __syncthreads();
    for (int k=threadIdx.x; k<IPB; k+=256){
        int j = base+k;
        if (j < nE){
            int n = nidx[j], e = eidx[j];
            int b1 = n>>8;
            int p1 = rsv[b1] + atomicAdd(&fl[b1], 1);
            pairs[p1] = ((u64)(u32)n << 32) | (u32)e;
            int k2 = nN + e;
            int b2 = k2>>8;
            int p2 = rsv[b2] + atomicAdd(&fl[b2], 1);
            pairs[p2] = ((u64)(u32)k2 << 32) | (u32)n;
        }
    }
}

// ---------- per-bucket fine counting sort in LDS: csr (coalesced) + off ----------
__global__ __launch_bounds__(256) void k_bucket(const u64* __restrict__ pairs, const int* __restrict__ bbase,
                                                int* __restrict__ csr, int* __restrict__ off, int nkeys){
    __shared__ int cntS[KPB];
    __shared__ int fillS[KPB];
    __shared__ int vals[CAP];
    int b = blockIdx.x;
    int t = threadIdx.x;
    int base = bbase[b];
    int n = bbase[b+1] - base;
    int k0 = b * KPB;

    cntS[t] = 0;
    __syncthreads();
    for (int i=t; i<n; i+=256){
        u64 p = pairs[base+i];
        int kl = (int)(p>>32) - k0;
        atomicAdd(&cntS[kl], 1);
    }
    __syncthreads();
    int c = cntS[t];
    __syncthreads();
    // Hillis-Steele inclusive scan over 256 in fillS as temp
    fillS[t] = c; __syncthreads();
    for (int o=1;o<256;o<<=1){ int u = (t>=o)? fillS[t-o] : 0; __syncthreads(); fillS[t]+=u; __syncthreads(); }
    int ex = fillS[t] - c;
    __syncthreads();
    cntS[t] = ex; fillS[t] = ex;
    __syncthreads();
    int k = k0 + t;
    if (k < nkeys) off[k] = base + ex;
    bool fits = (n <= CAP);
    for (int i=t; i<n; i+=256){
        u64 p = pairs[base+i];
        int kl = (int)(p>>32) - k0;
        int pos = atomicAdd(&fillS[kl], 1);
        if (fits) vals[pos] = (int)(u32)p;
        else      csr[base+pos] = (int)(u32)p;
    }
    __syncthreads();
    if (fits){
        for (int i=t; i<n; i+=256) csr[base+i] = vals[i];
    }
}

// ---------- MFMA GEMM (bf16 A): C[M x 128] = A[M x 128] @ W[128 x 128] ----------
__global__ __launch_bounds__(256) void k_gemm(const u16* __restrict__ A, const u16* __restrict__ Wf,
                                              u16* __restrict__ C, int M){
    int wave = blockIdx.x*4 + (threadIdx.x>>6);
    int lane = threadIdx.x & 63;
    int rtiles = M >> 4;
    if (wave >= rtiles) return;
    int row0 = wave << 4;

    const u16* Arow = A + (size_t)(row0 + (lane&15))*HID + ((lane>>4)<<3);
    const bf16x8* Wp = reinterpret_cast<const bf16x8*>(Wf) + lane;

    f32x4 acc[8];
    #pragma unroll
    for (int j=0;j<8;++j) acc[j] = (f32x4){0.f,0.f,0.f,0.f};

    #pragma unroll
    for (int s=0;s<4;++s){
        bf16x8 a = *reinterpret_cast<const bf16x8*>(Arow + s*32);
        #pragma unroll
        for (int j=0;j<8;++j){
            bf16x8 b = Wp[(s*8 + j)*64];
            acc[j] = __builtin_amdgcn_mfma_f32_16x16x32_bf16(a, b, acc[j], 0, 0, 0);
        }
    }
    int r0 = row0 + ((lane>>4)<<2);
    int c0 = lane & 15;
    #pragma unroll
    for (int j=0;j<8;++j){
        #pragma unroll
        for (int r=0;r<4;++r){
            C[(size_t)(r0+r)*HID + j*16 + c0] = (u16)f2bfu(acc[j][r]);
        }
    }
}

// ---------- MFMA GEMM (fp32 A, in-register bf16 convert): saves the x->bf16 pass ----------
__global__ __launch_bounds__(256) void k_gemm_f32(const float* __restrict__ A, const u16* __restrict__ Wf,
                                                  u16* __restrict__ C, int M){
    int wave = blockIdx.x*4 + (threadIdx.x>>6);
    int lane = threadIdx.x & 63;
    int rtiles = M >> 4;
    if (wave >= rtiles) return;
    int row0 = wave << 4;

    const float* Arow = A + (size_t)(row0 + (lane&15))*HID + ((lane>>4)<<3);
    const bf16x8* Wp = reinterpret_cast<const bf16x8*>(Wf) + lane;

    f32x4 acc[8];
    #pragma unroll
    for (int j=0;j<8;++j) acc[j] = (f32x4){0.f,0.f,0.f,0.f};

    #pragma unroll
    for (int s=0;s<4;++s){
        float4 f0 = *reinterpret_cast<const float4*>(Arow + s*32);
        float4 f1 = *reinterpret_cast<const float4*>(Arow + s*32 + 4);
        union { u16 h[8]; bf16x8 v; } au;
        au.h[0]=(u16)f2bfu(f0.x); au.h[1]=(u16)f2bfu(f0.y); au.h[2]=(u16)f2bfu(f0.z); au.h[3]=(u16)f2bfu(f0.w);
        au.h[4]=(u16)f2bfu(f1.x); au.h[5]=(u16)f2bfu(f1.y); au.h[6]=(u16)f2bfu(f1.z); au.h[7]=(u16)f2bfu(f1.w);
        #pragma unroll
        for (int j=0;j<8;++j){
            bf16x8 b = Wp[(s*8 + j)*64];
            acc[j] = __builtin_amdgcn_mfma_f32_16x16x32_bf16(au.v, b, acc[j], 0, 0, 0);
        }
    }
    int r0 = row0 + ((lane>>4)<<2);
    int c0 = lane & 15;
    #pragma unroll
    for (int j=0;j<8;++j){
        #pragma unroll
        for (int r=0;r<4;++r){
            C[(size_t)(r0+r)*HID + j*16 + c0] = (u16)f2bfu(acc[j][r]);
        }
    }
}

// ---------- CSR-gather segment mean, dwordx4 ----------
// one wave per dest row; 4 groups x 16 lanes; group g loads source row j+g,
// lane chunk c covers cols [8c, 8c+8) as 4 u32 (16B dwordx4).
// MODE 0: out bf16 row-major, scale only
// MODE 1: out bf16 row-major, scale + bias + prelu
// MODE 2: out fp32 row-major, scale + bias + residual + prelu
template<int MODE>
__global__ __launch_bounds__(256) void k_agg(const u32* __restrict__ tab, const int* __restrict__ csr,
                                             const int* __restrict__ off, void* __restrict__ outp,
                                             const float* __restrict__ bias, const float* __restrict__ resid,
                                             const float* __restrict__ aptr, int nrows){
    int d = blockIdx.x*4 + (threadIdx.x>>6);
    if (d >= nrows) return;
    int lane = threadIdx.x & 63;
    int g = lane >> 4;
    int c = lane & 15;
    int start = off[d], end = off[d+1];
    int deg = end - start;

    int myc = 0;
    if (lane < deg) myc = csr[start + lane];

    float a0=0.f,a1=0.f,a2=0.f,a3=0.f,a4=0.f,a5=0.f,a6=0.f,a7=0.f;
    int nb4 = deg < 64 ? deg : 64;
    for (int jb = 0; jb < nb4; jb += 4){
        int j = jb + g;
        int src = __shfl(myc, j, 64);
        uint4 v = make_uint4(0u,0u,0u,0u);
        if (j < nb4) v = *reinterpret_cast<const uint4*>(tab + (size_t)src*64 + (c<<2));
        a0 += blo(v.x); a1 += bhi(v.x);
        a2 += blo(v.y); a3 += bhi(v.y);
        a4 += blo(v.z); a5 += bhi(v.z);
        a6 += blo(v.w); a7 += bhi(v.w);
    }
    for (int j = start + 64; j < end; ++j){
        uint4 v = make_uint4(0u,0u,0u,0u);
        if (g == 0){
            int src = csr[j];
            v = *reinterpret_cast<const uint4*>(tab + (size_t)src*64 + (c<<2));
        }
        a0 += blo(v.x); a1 += bhi(v.x);
        a2 += blo(v.y); a3 += bhi(v.y);
        a4 += blo(v.z); a5 += bhi(v.z);
        a6 += blo(v.w); a7 += bhi(v.w);
    }
    a0 += __shfl_xor(a0,16,64); a0 += __shfl_xor(a0,32,64);
    a1 += __shfl_xor(a1,16,64); a1 += __shfl_xor(a1,32,64);
    a2 += __shfl_xor(a2,16,64); a2 += __shfl_xor(a2,32,64);
    a3 += __shfl_xor(a3,16,64); a3 += __shfl_xor(a3,32,64);
    a4 += __shfl_xor(a4,16,64); a4 += __shfl_xor(a4,32,64);
    a5 += __shfl_xor(a5,16,64); a5 += __shfl_xor(a5,32,64);
    a6 += __shfl_xor(a6,16,64); a6 += __shfl_xor(a6,32,64);
    a7 += __shfl_xor(a7,16,64); a7 += __shfl_xor(a7,32,64);

    if (g == 0){
        float s = (deg > 0) ? 1.0f/(float)deg : 0.f;
        a0*=s; a1*=s; a2*=s; a3*=s; a4*=s; a5*=s; a6*=s; a7*=s;
        if constexpr (MODE >= 1){
            float4 b0 = *reinterpret_cast<const float4*>(bias + (c<<3));
            float4 b1v = *reinterpret_cast<const float4*>(bias + (c<<3) + 4);
            a0+=b0.x; a1+=b0.y; a2+=b0.z; a3+=b0.w;
            a4+=b1v.x; a5+=b1v.y; a6+=b1v.z; a7+=b1v.w;
        }
        if constexpr (MODE == 2){
            const float* rp = resid + (size_t)d*HID + (c<<3);
            float4 r0 = *reinterpret_cast<const float4*>(rp);
            float4 r1 = *reinterpret_cast<const float4*>(rp + 4);
            a0+=r0.x; a1+=r0.y; a2+=r0.z; a3+=r0.w;
            a4+=r1.x; a5+=r1.y; a6+=r1.z; a7+=r1.w;
        }
        if constexpr (MODE >= 1){
            float al = aptr[0];
            a0 = (a0>=0.f)? a0 : al*a0;  a1 = (a1>=0.f)? a1 : al*a1;
            a2 = (a2>=0.f)? a2 : al*a2;  a3 = (a3>=0.f)? a3 : al*a3;
            a4 = (a4>=0.f)? a4 : al*a4;  a5 = (a5>=0.f)? a5 : al*a5;
            a6 = (a6>=0.f)? a6 : al*a6;  a7 = (a7>=0.f)? a7 : al*a7;
        }
        if constexpr (MODE == 2){
            float* op = (float*)outp + (size_t)d*HID + (c<<3);
            *reinterpret_cast<float4*>(op)     = make_float4(a0,a1,a2,a3);
            *reinterpret_cast<float4*>(op + 4) = make_float4(a4,a5,a6,a7);
        } else {
            uint4 wv;
            wv.x = pk(a0,a1); wv.y = pk(a2,a3); wv.z = pk(a4,a5); wv.w = pk(a6,a7);
            *reinterpret_cast<uint4*>((u32*)outp + (size_t)d*64 + (c<<2)) = wv;
        }
    }
}

extern "C" void kernel_launch(void* const* d_in, const int* in_sizes, int n_in,
                              void* d_out, int out_size, void* d_ws, size_t ws_size,
                              hipStream_t stream){
    (void)n_in; (void)out_size; (void)ws_size;
    const float* x  = (const float*)d_in[0];
    const int*  hei = (const int*)  d_in[1];
    const float* W1 = (const float*)d_in[2];
    const float* b1 = (const float*)d_in[3];
    const float* W2 = (const float*)d_in[4];
    const float* b2 = (const float*)d_in[5];
    const float* ap = (const float*)d_in[6];

    const int nN = in_sizes[0] / HID;   // 50000
    const int nE = in_sizes[1] / 2;     // 600000
    const int* nidx = hei;
    const int* eidx = hei + nE;
    const int nkeys = 2*nN;
    const int nb    = (nkeys + KPB - 1) / KPB;   // 391

    char* w = (char*)d_ws;
    size_t o = 0;
    auto alloc = [&](size_t bytes)->void*{
        void* p = (void*)(w + o);
        o += (bytes + 255) & ~(size_t)255;
        return p;
    };
    int* hist  = (int*)alloc((size_t)NBMAX*sizeof(int));
    int* bbase = (int*)alloc((size_t)(NBMAX+1)*sizeof(int));
    int* bfill = (int*)alloc((size_t)NBMAX*sizeof(int));
    int* off   = (int*)alloc(((size_t)nkeys+1)*sizeof(int));
    int* csr   = (int*)alloc((size_t)2*nE*sizeof(int));
    u64* pairs = (u64*)alloc((size_t)2*nE*sizeof(u64));
    u16* hb    = (u16*)alloc((size_t)nN*HID*sizeof(u16));   // h bf16 (layer-1 output)
    u16* bufB  = (u16*)alloc((size_t)nN*HID*sizeof(u16));   // xw / hw
    u16* bufC  = (u16*)alloc((size_t)nN*HID*sizeof(u16));   // m / m2
    u16* w1f   = (u16*)alloc((size_t)HID*HID*sizeof(u16));
    u16* w2f   = (u16*)alloc((size_t)HID*HID*sizeof(u16));

    hipMemsetAsync(hist, 0, (size_t)nb*sizeof(int), stream);

    k_wfrag2<<<128, 256, 0, stream>>>(W1, W2, w1f, w2f);

    const int rtiles = nN/16;
    const int ggrid  = (rtiles + 3)/4;
    k_gemm_f32<<<ggrid, 256, 0, stream>>>(x, w1f, bufB, nN);   // xw = x @ W1 (fp32 A)

    const int pgrid = (nE + IPB - 1)/IPB;       // 293
    k_hist <<<pgrid, 256, 0, stream>>>(nidx, eidx, hist, nE, nN, nb);
    k_bscan<<<1,     256, 0, stream>>>(hist, bbase, bfill, off, nb, nkeys, 2*nE);
    k_part <<<pgrid, 256, 0, stream>>>(nidx, eidx, bfill, pairs, nE, nN, nb);
    k_bucket<<<nb,   256, 0, stream>>>(pairs, bbase, csr, off, nkeys);

    const int agrid  = (nN + 3)/4;

    // layer 1
    k_agg<0><<<agrid, 256, 0, stream>>>((const u32*)bufB, csr, off + nN, bufC, nullptr, nullptr, nullptr, nN);
    k_agg<1><<<agrid, 256, 0, stream>>>((const u32*)bufC, csr, off,      hb,   b1, nullptr, ap, nN);
    // layer 2
    k_gemm<<<ggrid, 256, 0, stream>>>(hb, w2f, bufB, nN);
    k_agg<0><<<agrid, 256, 0, stream>>>((const u32*)bufB, csr, off + nN, bufC, nullptr, nullptr, nullptr, nN);
    k_agg<2><<<agrid, 256, 0, stream>>>((const u32*)bufC, csr, off, d_out, b2, x, ap, nN);
}

// Round 6
// 239.799 us; speedup vs baseline: 1.7471x; 1.0557x over previous
//
#include <hip/hip_runtime.h>

typedef unsigned short u16;
typedef unsigned int   u32;
typedef unsigned long long u64;

#define HID 128
#define KPB 256      // keys per coarse bucket (shift 8)
#define NBMAX 512    // max coarse buckets (actual: 391)
#define IPB 2048     // incidences per partition workgroup
#define CAP 6144     // LDS val-staging capacity per bucket (mean ~3070)

typedef __bf16 bf16x8 __attribute__((ext_vector_type(8)));
typedef float  f32x4  __attribute__((ext_vector_type(4)));

__device__ inline float u2f(u32 u){ union{u32 u;float f;} v; v.u=u; return v.f; }
__device__ inline u32   f2u(float f){ union{float f;u32 u;} v; v.f=f; return v.u; }
__device__ inline u32  f2bfu(float f){ u32 b=f2u(f); return ((b + 0x7FFFu + ((b>>16)&1u))>>16)&0xFFFFu; }
__device__ inline float blo(u32 u){ return u2f(u<<16); }
__device__ inline float bhi(u32 u){ return u2f(u & 0xFFFF0000u); }
__device__ inline u32  pk(float lo, float hi){ return (f2bfu(hi)<<16) | f2bfu(lo); }

// ---------- W1,W2 -> MFMA B-fragment bf16; also zeroes hist/bfill, writes off sentinel ----------
__global__ __launch_bounds__(256) void k_wfrag2(const float* __restrict__ W1, const float* __restrict__ W2,
                                                u16* __restrict__ W1f, u16* __restrict__ W2f,
                                                int* __restrict__ hist, int* __restrict__ bfill,
                                                int* __restrict__ off, int nkeys, int total){
    int gid = blockIdx.x*256 + threadIdx.x;   // 32768 total
    if (gid < NBMAX){ hist[gid] = 0; bfill[gid] = 0; }
    if (gid == 0) off[nkeys] = total;
    const float* W = (gid < 16384) ? W1 : W2;
    u16* Wf = (gid < 16384) ? W1f : W2f;
    int id = gid & 16383;
    int i = id & 7, l = (id>>3)&63, j = (id>>9)&7, s = id>>12;
    int k = s*32 + ((l>>4)<<3) + i;
    int n = (j<<4) + (l&15);
    Wf[id] = (u16)f2bfu(W[k*HID + n]);
}

// ---------- coarse histogram over combined key space [0, 2*nN) ----------
__global__ __launch_bounds__(256) void k_hist(const int* __restrict__ nidx, const int* __restrict__ eidx,
                                              int* __restrict__ hist, int nE, int nN, int nb){
    __shared__ int h[NBMAX];
    for (int t=threadIdx.x; t<nb; t+=256) h[t]=0;
    __syncthreads();
    int base = blockIdx.x*IPB;
    for (int k=threadIdx.x; k<IPB; k+=256){
        int j = base+k;
        if (j < nE){
            int n = nidx[j], e = eidx[j];
            atomicAdd(&h[n>>8], 1);
            atomicAdd(&h[(nN+e)>>8], 1);
        }
    }
    __syncthreads();
    for (int t=threadIdx.x; t<nb; t+=256) if (h[t]) atomicAdd(&hist[t], h[t]);
}

// ---------- partition into coarse buckets (computes bucket bases locally) ----------
__global__ __launch_bounds__(256) void k_part(const int* __restrict__ nidx, const int* __restrict__ eidx,
                                              const int* __restrict__ hist, int* __restrict__ bfill,
                                              u64* __restrict__ pairs, int nE, int nN, int nb){
    __shared__ int h[NBMAX], rsv[NBMAX], fl[NBMAX], bb[NBMAX], sd[256];
    int t = threadIdx.x;
    for (int i=t; i<nb; i+=256){ h[i]=0; fl[i]=0; }
    __syncthreads();
    int base = blockIdx.x*IPB;
    for (int k=t; k<IPB; k+=256){
        int j = base+k;
        if (j < nE){
            int n = nidx[j], e = eidx[j];
            atomicAdd(&h[n>>8], 1);
            atomicAdd(&h[(nN+e)>>8], 1);
        }
    }
    // local exclusive scan of global hist -> bb
    int c0 = (2*t   < nb) ? hist[2*t]   : 0;
    int c1 = (2*t+1 < nb) ? hist[2*t+1] : 0;
    int s = c0 + c1;
    sd[t] = s; __syncthreads();
    for (int o=1;o<256;o<<=1){ int u = (t>=o)? sd[t-o] : 0; __syncthreads(); sd[t]+=u; __syncthreads(); }
    int ex = sd[t] - s;
    if (2*t   < nb) bb[2*t]   = ex;
    if (2*t+1 < nb) bb[2*t+1] = ex + c0;
    __syncthreads();
    for (int i=t; i<nb; i+=256){ if (h[i]) rsv[i] = bb[i] + atomicAdd(&bfill[i], h[i]); }
    __syncthreads();
    for (int k=t; k<IPB; k+=256){
        int j = base+k;
        if (j < nE){
            int n = nidx[j], e = eidx[j];
            int b1 = n>>8;
            int p1 = rsv[b1] + atomicAdd(&fl[b1], 1);
            pairs[p1] = ((u64)(u32)n << 32) | (u32)e;
            int k2 = nN + e;
            int b2 = k2>>8;
            int p2 = rsv[b2] + atomicAdd(&fl[b2], 1);
            pairs[p2] = ((u64)(u32)k2 << 32) | (u32)n;
        }
    }
}

// ---------- per-bucket fine counting sort in LDS (computes own base locally) ----------
__global__ __launch_bounds__(256) void k_bucket(const u64* __restrict__ pairs, const int* __restrict__ hist,
                                                int* __restrict__ csr, int* __restrict__ off,
                                                int nkeys, int nb){
    __shared__ int cntS[KPB];
    __shared__ int fillS[KPB];
    __shared__ int bbS[NBMAX+1];
    __shared__ int sd[256];
    __shared__ int vals[CAP];
    int b = blockIdx.x;
    int t = threadIdx.x;
    // local exclusive scan of hist -> bbS[0..nb]
    int c0 = (2*t   < nb) ? hist[2*t]   : 0;
    int c1 = (2*t+1 < nb) ? hist[2*t+1] : 0;
    int s = c0 + c1;
    sd[t] = s; __syncthreads();
    for (int o=1;o<256;o<<=1){ int u = (t>=o)? sd[t-o] : 0; __syncthreads(); sd[t]+=u; __syncthreads(); }
    int ex = sd[t] - s;
    if (2*t   <= nb) bbS[2*t]   = ex;
    if (2*t+1 <= nb) bbS[2*t+1] = ex + c0;
    __syncthreads();
    int base = bbS[b];
    int n = bbS[b+1] - base;
    int k0 = b * KPB;

    cntS[t] = 0;
    __syncthreads();
    for (int i=t; i<n; i+=256){
        u64 p = pairs[base+i];
        int kl = (int)(p>>32) - k0;
        atomicAdd(&cntS[kl], 1);
    }
    __syncthreads();
    int c = cntS[t];
    __syncthreads();
    fillS[t] = c; __syncthreads();
    for (int o=1;o<256;o<<=1){ int u = (t>=o)? fillS[t-o] : 0; __syncthreads(); fillS[t]+=u; __syncthreads(); }
    int ex2 = fillS[t] - c;
    __syncthreads();
    cntS[t] = ex2; fillS[t] = ex2;
    __syncthreads();
    int k = k0 + t;
    if (k < nkeys) off[k] = base + ex2;
    bool fits = (n <= CAP);
    for (int i=t; i<n; i+=256){
        u64 p = pairs[base+i];
        int kl = (int)(p>>32) - k0;
        int pos = atomicAdd(&fillS[kl], 1);
        if (fits) vals[pos] = (int)(u32)p;
        else      csr[base+pos] = (int)(u32)p;
    }
    __syncthreads();
    if (fits){
        for (int i=t; i<n; i+=256) csr[base+i] = vals[i];
    }
}

// ---------- MFMA GEMM (bf16 A): C[M x 128] = A[M x 128] @ W[128 x 128] ----------
__global__ __launch_bounds__(256) void k_gemm(const u16* __restrict__ A, const u16* __restrict__ Wf,
                                              u16* __restrict__ C, int M){
    int wave = blockIdx.x*4 + (threadIdx.x>>6);
    int lane = threadIdx.x & 63;
    int rtiles = M >> 4;
    if (wave >= rtiles) return;
    int row0 = wave << 4;

    const u16* Arow = A + (size_t)(row0 + (lane&15))*HID + ((lane>>4)<<3);
    const bf16x8* Wp = reinterpret_cast<const bf16x8*>(Wf) + lane;

    f32x4 acc[8];
    #pragma unroll
    for (int j=0;j<8;++j) acc[j] = (f32x4){0.f,0.f,0.f,0.f};

    #pragma unroll
    for (int s=0;s<4;++s){
        bf16x8 a = *reinterpret_cast<const bf16x8*>(Arow + s*32);
        #pragma unroll
        for (int j=0;j<8;++j){
            bf16x8 b = Wp[(s*8 + j)*64];
            acc[j] = __builtin_amdgcn_mfma_f32_16x16x32_bf16(a, b, acc[j], 0, 0, 0);
        }
    }
    int r0 = row0 + ((lane>>4)<<2);
    int c0 = lane & 15;
    #pragma unroll
    for (int j=0;j<8;++j){
        #pragma unroll
        for (int r=0;r<4;++r){
            C[(size_t)(r0+r)*HID + j*16 + c0] = (u16)f2bfu(acc[j][r]);
        }
    }
}

// ---------- MFMA GEMM (fp32 A, in-register bf16 convert) ----------
__global__ __launch_bounds__(256) void k_gemm_f32(const float* __restrict__ A, const u16* __restrict__ Wf,
                                                  u16* __restrict__ C, int M){
    int wave = blockIdx.x*4 + (threadIdx.x>>6);
    int lane = threadIdx.x & 63;
    int rtiles = M >> 4;
    if (wave >= rtiles) return;
    int row0 = wave << 4;

    const float* Arow = A + (size_t)(row0 + (lane&15))*HID + ((lane>>4)<<3);
    const bf16x8* Wp = reinterpret_cast<const bf16x8*>(Wf) + lane;

    f32x4 acc[8];
    #pragma unroll
    for (int j=0;j<8;++j) acc[j] = (f32x4){0.f,0.f,0.f,0.f};

    #pragma unroll
    for (int s=0;s<4;++s){
        float4 f0 = *reinterpret_cast<const float4*>(Arow + s*32);
        float4 f1 = *reinterpret_cast<const float4*>(Arow + s*32 + 4);
        union { u16 h[8]; bf16x8 v; } au;
        au.h[0]=(u16)f2bfu(f0.x); au.h[1]=(u16)f2bfu(f0.y); au.h[2]=(u16)f2bfu(f0.z); au.h[3]=(u16)f2bfu(f0.w);
        au.h[4]=(u16)f2bfu(f1.x); au.h[5]=(u16)f2bfu(f1.y); au.h[6]=(u16)f2bfu(f1.z); au.h[7]=(u16)f2bfu(f1.w);
        #pragma unroll
        for (int j=0;j<8;++j){
            bf16x8 b = Wp[(s*8 + j)*64];
            acc[j] = __builtin_amdgcn_mfma_f32_16x16x32_bf16(au.v, b, acc[j], 0, 0, 0);
        }
    }
    int r0 = row0 + ((lane>>4)<<2);
    int c0 = lane & 15;
    #pragma unroll
    for (int j=0;j<8;++j){
        #pragma unroll
        for (int r=0;r<4;++r){
            C[(size_t)(r0+r)*HID + j*16 + c0] = (u16)f2bfu(acc[j][r]);
        }
    }
}

// ---------- CSR-gather segment mean, dwordx4, 16-row load batches (4 loads in flight) ----------
// one wave per dest row; 4 groups x 16 lanes; lane chunk c covers cols [8c,8c+8) (16B).
// MODE 0: out bf16, scale only | MODE 1: + bias + prelu | MODE 2: fp32 out, + bias + resid + prelu
template<int MODE>
__global__ __launch_bounds__(256) void k_agg(const u32* __restrict__ tab, const int* __restrict__ csr,
                                             const int* __restrict__ off, void* __restrict__ outp,
                                             const float* __restrict__ bias, const float* __restrict__ resid,
                                             const float* __restrict__ aptr, int nrows){
    int d = blockIdx.x*4 + (threadIdx.x>>6);
    if (d >= nrows) return;
    int lane = threadIdx.x & 63;
    int g = lane >> 4;
    int c = lane & 15;
    int start = off[d], end = off[d+1];
    int deg = end - start;

    int myc = 0;
    if (lane < deg) myc = csr[start + lane];

    float a0=0.f,a1=0.f,a2=0.f,a3=0.f,a4=0.f,a5=0.f,a6=0.f,a7=0.f;
    int nb4 = deg < 64 ? deg : 64;
    for (int jb = 0; jb < nb4; jb += 16){
        int j0 = jb + g, j1 = jb + 4 + g, j2 = jb + 8 + g, j3 = jb + 12 + g;
        int s0 = __shfl(myc, j0, 64);
        int s1 = __shfl(myc, j1, 64);
        int s2 = __shfl(myc, j2, 64);
        int s3 = __shfl(myc, j3, 64);
        uint4 v0 = make_uint4(0u,0u,0u,0u), v1 = v0, v2 = v0, v3 = v0;
        if (j0 < nb4) v0 = *reinterpret_cast<const uint4*>(tab + (size_t)s0*64 + (c<<2));
        if (j1 < nb4) v1 = *reinterpret_cast<const uint4*>(tab + (size_t)s1*64 + (c<<2));
        if (j2 < nb4) v2 = *reinterpret_cast<const uint4*>(tab + (size_t)s2*64 + (c<<2));
        if (j3 < nb4) v3 = *reinterpret_cast<const uint4*>(tab + (size_t)s3*64 + (c<<2));
        a0 += blo(v0.x)+blo(v1.x)+blo(v2.x)+blo(v3.x);
        a1 += bhi(v0.x)+bhi(v1.x)+bhi(v2.x)+bhi(v3.x);
        a2 += blo(v0.y)+blo(v1.y)+blo(v2.y)+blo(v3.y);
        a3 += bhi(v0.y)+bhi(v1.y)+bhi(v2.y)+bhi(v3.y);
        a4 += blo(v0.z)+blo(v1.z)+blo(v2.z)+blo(v3.z);
        a5 += bhi(v0.z)+bhi(v1.z)+bhi(v2.z)+bhi(v3.z);
        a6 += blo(v0.w)+blo(v1.w)+blo(v2.w)+blo(v3.w);
        a7 += bhi(v0.w)+bhi(v1.w)+bhi(v2.w)+bhi(v3.w);
    }
    for (int j = start + 64; j < end; ++j){
        uint4 v = make_uint4(0u,0u,0u,0u);
        if (g == 0){
            int src = csr[j];
            v = *reinterpret_cast<const uint4*>(tab + (size_t)src*64 + (c<<2));
        }
        a0 += blo(v.x); a1 += bhi(v.x);
        a2 += blo(v.y); a3 += bhi(v.y);
        a4 += blo(v.z); a5 += bhi(v.z);
        a6 += blo(v.w); a7 += bhi(v.w);
    }
    a0 += __shfl_xor(a0,16,64); a0 += __shfl_xor(a0,32,64);
    a1 += __shfl_xor(a1,16,64); a1 += __shfl_xor(a1,32,64);
    a2 += __shfl_xor(a2,16,64); a2 += __shfl_xor(a2,32,64);
    a3 += __shfl_xor(a3,16,64); a3 += __shfl_xor(a3,32,64);
    a4 += __shfl_xor(a4,16,64); a4 += __shfl_xor(a4,32,64);
    a5 += __shfl_xor(a5,16,64); a5 += __shfl_xor(a5,32,64);
    a6 += __shfl_xor(a6,16,64); a6 += __shfl_xor(a6,32,64);
    a7 += __shfl_xor(a7,16,64); a7 += __shfl_xor(a7,32,64);

    if (g == 0){
        float s = (deg > 0) ? 1.0f/(float)deg : 0.f;
        a0*=s; a1*=s; a2*=s; a3*=s; a4*=s; a5*=s; a6*=s; a7*=s;
        if constexpr (MODE >= 1){
            float4 b0 = *reinterpret_cast<const float4*>(bias + (c<<3));
            float4 b1v = *reinterpret_cast<const float4*>(bias + (c<<3) + 4);
            a0+=b0.x; a1+=b0.y; a2+=b0.z; a3+=b0.w;
            a4+=b1v.x; a5+=b1v.y; a6+=b1v.z; a7+=b1v.w;
        }
        if constexpr (MODE == 2){
            const float* rp = resid + (size_t)d*HID + (c<<3);
            float4 r0 = *reinterpret_cast<const float4*>(rp);
            float4 r1 = *reinterpret_cast<const float4*>(rp + 4);
            a0+=r0.x; a1+=r0.y; a2+=r0.z; a3+=r0.w;
            a4+=r1.x; a5+=r1.y; a6+=r1.z; a7+=r1.w;
        }
        if constexpr (MODE >= 1){
            float al = aptr[0];
            a0 = (a0>=0.f)? a0 : al*a0;  a1 = (a1>=0.f)? a1 : al*a1;
            a2 = (a2>=0.f)? a2 : al*a2;  a3 = (a3>=0.f)? a3 : al*a3;
            a4 = (a4>=0.f)? a4 : al*a4;  a5 = (a5>=0.f)? a5 : al*a5;
            a6 = (a6>=0.f)? a6 : al*a6;  a7 = (a7>=0.f)? a7 : al*a7;
        }
        if constexpr (MODE == 2){
            float* op = (float*)outp + (size_t)d*HID + (c<<3);
            *reinterpret_cast<float4*>(op)     = make_float4(a0,a1,a2,a3);
            *reinterpret_cast<float4*>(op + 4) = make_float4(a4,a5,a6,a7);
        } else {
            uint4 wv;
            wv.x = pk(a0,a1); wv.y = pk(a2,a3); wv.z = pk(a4,a5); wv.w = pk(a6,a7);
            *reinterpret_cast<uint4*>((u32*)outp + (size_t)d*64 + (c<<2)) = wv;
        }
    }
}

extern "C" void kernel_launch(void* const* d_in, const int* in_sizes, int n_in,
                              void* d_out, int out_size, void* d_ws, size_t ws_size,
                              hipStream_t stream){
    (void)n_in; (void)out_size; (void)ws_size;
    const float* x  = (const float*)d_in[0];
    const int*  hei = (const int*)  d_in[1];
    const float* W1 = (const float*)d_in[2];
    const float* b1 = (const float*)d_in[3];
    const float* W2 = (const float*)d_in[4];
    const float* b2 = (const float*)d_in[5];
    const float* ap = (const float*)d_in[6];

    const int nN = in_sizes[0] / HID;   // 50000
    const int nE = in_sizes[1] / 2;     // 600000
    const int* nidx = hei;
    const int* eidx = hei + nE;
    const int nkeys = 2*nN;
    const int nb    = (nkeys + KPB - 1) / KPB;   // 391

    char* w = (char*)d_ws;
    size_t o = 0;
    auto alloc = [&](size_t bytes)->void*{
        void* p = (void*)(w + o);
        o += (bytes + 255) & ~(size_t)255;
        return p;
    };
    int* hist  = (int*)alloc((size_t)NBMAX*sizeof(int));
    int* bfill = (int*)alloc((size_t)NBMAX*sizeof(int));
    int* off   = (int*)alloc(((size_t)nkeys+1)*sizeof(int));
    int* csr   = (int*)alloc((size_t)2*nE*sizeof(int));
    u64* pairs = (u64*)alloc((size_t)2*nE*sizeof(u64));
    u16* hb    = (u16*)alloc((size_t)nN*HID*sizeof(u16));   // h bf16 (layer-1 output)
    u16* bufB  = (u16*)alloc((size_t)nN*HID*sizeof(u16));   // xw / hw
    u16* bufC  = (u16*)alloc((size_t)nN*HID*sizeof(u16));   // m / m2
    u16* w1f   = (u16*)alloc((size_t)HID*HID*sizeof(u16));
    u16* w2f   = (u16*)alloc((size_t)HID*HID*sizeof(u16));

    k_wfrag2<<<128, 256, 0, stream>>>(W1, W2, w1f, w2f, hist, bfill, off, nkeys, 2*nE);

    const int rtiles = nN/16;
    const int ggrid  = (rtiles + 3)/4;
    k_gemm_f32<<<ggrid, 256, 0, stream>>>(x, w1f, bufB, nN);   // xw = x @ W1 (fp32 A)

    const int pgrid = (nE + IPB - 1)/IPB;       // 293
    k_hist  <<<pgrid, 256, 0, stream>>>(nidx, eidx, hist, nE, nN, nb);
    k_part  <<<pgrid, 256, 0, stream>>>(nidx, eidx, hist, bfill, pairs, nE, nN, nb);
    k_bucket<<<nb,    256, 0, stream>>>(pairs, hist, csr, off, nkeys, nb);

    const int agrid  = (nN + 3)/4;

    // layer 1
    k_agg<0><<<agrid, 256, 0, stream>>>((const u32*)bufB, csr, off + nN, bufC, nullptr, nullptr, nullptr, nN);
    k_agg<1><<<agrid, 256, 0, stream>>>((const u32*)bufC, csr, off,      hb,   b1, nullptr, ap, nN);
    // layer 2
    k_gemm<<<ggrid, 256, 0, stream>>>(hb, w2f, bufB, nN);
    k_agg<0><<<agrid, 256, 0, stream>>>((const u32*)bufB, csr, off + nN, bufC, nullptr, nullptr, nullptr, nN);
    k_agg<2><<<agrid, 256, 0, stream>>>((const u32*)bufC, csr, off, d_out, b2, x, ap, nN);
}

// Round 7
// 233.460 us; speedup vs baseline: 1.7946x; 1.0272x over previous
//
#include <hip/hip_runtime.h>

typedef unsigned short u16;
typedef unsigned int   u32;
typedef unsigned long long u64;

#define HID 128
#define KPB 256      // keys per coarse bucket (shift 8)
#define NBMAX 512    // max coarse buckets (actual: 391)
#define IPB 2048     // incidences per partition workgroup
#define CAP 6144     // LDS val-staging capacity per bucket (mean ~3070)

typedef __bf16 bf16x8 __attribute__((ext_vector_type(8)));
typedef float  f32x4  __attribute__((ext_vector_type(4)));

__device__ inline float u2f(u32 u){ union{u32 u;float f;} v; v.u=u; return v.f; }
__device__ inline u32   f2u(float f){ union{float f;u32 u;} v; v.f=f; return v.u; }
__device__ inline u32  f2bfu(float f){ u32 b=f2u(f); return ((b + 0x7FFFu + ((b>>16)&1u))>>16)&0xFFFFu; }
__device__ inline float blo(u32 u){ return u2f(u<<16); }
__device__ inline float bhi(u32 u){ return u2f(u & 0xFFFF0000u); }
__device__ inline u32  pk(float lo, float hi){ return (f2bfu(hi)<<16) | f2bfu(lo); }

// ---------- K1: coarse histogram (blocks [0,nhb)) ∪ W-fragment conversion (rest) ----------
__global__ __launch_bounds__(256) void k_hist_wfrag(const int* __restrict__ nidx, const int* __restrict__ eidx,
                                                    int* __restrict__ hist, int nE, int nN, int nb, int nhb,
                                                    const float* __restrict__ W1, const float* __restrict__ W2,
                                                    u16* __restrict__ W1f, u16* __restrict__ W2f){
    __shared__ int h[NBMAX];
    if ((int)blockIdx.x < nhb){
        for (int t=threadIdx.x; t<nb; t+=256) h[t]=0;
        __syncthreads();
        int base = blockIdx.x*IPB;
        for (int k=threadIdx.x; k<IPB; k+=256){
            int j = base+k;
            if (j < nE){
                atomicAdd(&h[nidx[j]>>8], 1);
                atomicAdd(&h[(nN+eidx[j])>>8], 1);
            }
        }
        __syncthreads();
        for (int t=threadIdx.x; t<nb; t+=256) if (h[t]) atomicAdd(&hist[t], h[t]);
    } else {
        int gid = ((int)blockIdx.x - nhb)*256 + threadIdx.x;   // 32768 total
        const float* W = (gid < 16384) ? W1 : W2;
        u16* Wf = (gid < 16384) ? W1f : W2f;
        int id = gid & 16383;
        int i = id & 7, l = (id>>3)&63, j = (id>>9)&7, s = id>>12;
        Wf[id] = (u16)f2bfu(W[(s*32 + ((l>>4)<<3) + i)*HID + (j<<4) + (l&15)]);
    }
}

// ---------- K2: partition into buckets (blocks [0,npb)) ∪ layer-1 GEMM fp32-A (rest) ----------
__global__ __launch_bounds__(256) void k_part_gemm(const int* __restrict__ nidx, const int* __restrict__ eidx,
                                                   const int* __restrict__ hist, int* __restrict__ bfill,
                                                   u64* __restrict__ pairs, int nE, int nN, int nb, int npb,
                                                   const float* __restrict__ A, const u16* __restrict__ Wf,
                                                   u16* __restrict__ C, int M){
    __shared__ int h[NBMAX], rsv[NBMAX], fl[NBMAX], bb[NBMAX], sd[256];
    int t = threadIdx.x;
    if ((int)blockIdx.x < npb){
        for (int i=t; i<nb; i+=256){ h[i]=0; fl[i]=0; }
        __syncthreads();
        int base = blockIdx.x*IPB;
        for (int k=t; k<IPB; k+=256){
            int j = base+k;
            if (j < nE){
                atomicAdd(&h[nidx[j]>>8], 1);
                atomicAdd(&h[(nN+eidx[j])>>8], 1);
            }
        }
        int c0 = (2*t   < nb) ? hist[2*t]   : 0;
        int c1 = (2*t+1 < nb) ? hist[2*t+1] : 0;
        int s = c0 + c1;
        sd[t] = s; __syncthreads();
        for (int o=1;o<256;o<<=1){ int u = (t>=o)? sd[t-o] : 0; __syncthreads(); sd[t]+=u; __syncthreads(); }
        int ex = sd[t] - s;
        if (2*t   < nb) bb[2*t]   = ex;
        if (2*t+1 < nb) bb[2*t+1] = ex + c0;
        __syncthreads();
        for (int i=t; i<nb; i+=256){ if (h[i]) rsv[i] = bb[i] + atomicAdd(&bfill[i], h[i]); }
        __syncthreads();
        for (int k=t; k<IPB; k+=256){
            int j = base+k;
            if (j < nE){
                int n = nidx[j], e = eidx[j];
                int b1 = n>>8;
                int p1 = rsv[b1] + atomicAdd(&fl[b1], 1);
                pairs[p1] = ((u64)(u32)n << 32) | (u32)e;
                int k2 = nN + e;
                int b2 = k2>>8;
                int p2 = rsv[b2] + atomicAdd(&fl[b2], 1);
                pairs[p2] = ((u64)(u32)k2 << 32) | (u32)n;
            }
        }
    } else {
        int wave = ((int)blockIdx.x - npb)*4 + (t>>6);
        int lane = t & 63;
        int rtiles = M >> 4;
        if (wave >= rtiles) return;
        int row0 = wave << 4;
        const float* Arow = A + (size_t)(row0 + (lane&15))*HID + ((lane>>4)<<3);
        const bf16x8* Wp = reinterpret_cast<const bf16x8*>(Wf) + lane;
        f32x4 acc[8];
        #pragma unroll
        for (int j=0;j<8;++j) acc[j] = (f32x4){0.f,0.f,0.f,0.f};
        #pragma unroll
        for (int s=0;s<4;++s){
            float4 f0 = *reinterpret_cast<const float4*>(Arow + s*32);
            float4 f1 = *reinterpret_cast<const float4*>(Arow + s*32 + 4);
            union { u16 h[8]; bf16x8 v; } au;
            au.h[0]=(u16)f2bfu(f0.x); au.h[1]=(u16)f2bfu(f0.y); au.h[2]=(u16)f2bfu(f0.z); au.h[3]=(u16)f2bfu(f0.w);
            au.h[4]=(u16)f2bfu(f1.x); au.h[5]=(u16)f2bfu(f1.y); au.h[6]=(u16)f2bfu(f1.z); au.h[7]=(u16)f2bfu(f1.w);
            #pragma unroll
            for (int j=0;j<8;++j){
                bf16x8 b = Wp[(s*8 + j)*64];
                acc[j] = __builtin_amdgcn_mfma_f32_16x16x32_bf16(au.v, b, acc[j], 0, 0, 0);
            }
        }
        int r0 = row0 + ((lane>>4)<<2);
        int c0 = lane & 15;
        #pragma unroll
        for (int j=0;j<8;++j){
            #pragma unroll
            for (int r=0;r<4;++r){
                C[(size_t)(r0+r)*HID + j*16 + c0] = (u16)f2bfu(acc[j][r]);
            }
        }
    }
}

// ---------- per-bucket fine counting sort in LDS (computes own base locally) ----------
__global__ __launch_bounds__(256) void k_bucket(const u64* __restrict__ pairs, const int* __restrict__ hist,
                                                int* __restrict__ csr, int* __restrict__ off,
                                                int nkeys, int nb, int total){
    __shared__ int cntS[KPB];
    __shared__ int fillS[KPB];
    __shared__ int bbS[NBMAX+1];
    __shared__ int sd[256];
    __shared__ int vals[CAP];
    int b = blockIdx.x;
    int t = threadIdx.x;
    if (b == 0 && t == 0) off[nkeys] = total;
    int c0 = (2*t   < nb) ? hist[2*t]   : 0;
    int c1 = (2*t+1 < nb) ? hist[2*t+1] : 0;
    int s = c0 + c1;
    sd[t] = s; __syncthreads();
    for (int o=1;o<256;o<<=1){ int u = (t>=o)? sd[t-o] : 0; __syncthreads(); sd[t]+=u; __syncthreads(); }
    int ex = sd[t] - s;
    if (2*t   <= nb) bbS[2*t]   = ex;
    if (2*t+1 <= nb) bbS[2*t+1] = ex + c0;
    __syncthreads();
    int base = bbS[b];
    int n = bbS[b+1] - base;
    int k0 = b * KPB;

    cntS[t] = 0;
    __syncthreads();
    for (int i=t; i<n; i+=256){
        u64 p = pairs[base+i];
        atomicAdd(&cntS[(int)(p>>32) - k0], 1);
    }
    __syncthreads();
    int c = cntS[t];
    __syncthreads();
    fillS[t] = c; __syncthreads();
    for (int o=1;o<256;o<<=1){ int u = (t>=o)? fillS[t-o] : 0; __syncthreads(); fillS[t]+=u; __syncthreads(); }
    int ex2 = fillS[t] - c;
    __syncthreads();
    fillS[t] = ex2;
    __syncthreads();
    int k = k0 + t;
    if (k < nkeys) off[k] = base + ex2;
    bool fits = (n <= CAP);
    for (int i=t; i<n; i+=256){
        u64 p = pairs[base+i];
        int kl = (int)(p>>32) - k0;
        int pos = atomicAdd(&fillS[kl], 1);
        if (fits) vals[pos] = (int)(u32)p;
        else      csr[base+pos] = (int)(u32)p;
    }
    __syncthreads();
    if (fits){
        for (int i=t; i<n; i+=256) csr[base+i] = vals[i];
    }
}

// ---------- MFMA GEMM (bf16 A): C[M x 128] = A[M x 128] @ W[128 x 128] ----------
__global__ __launch_bounds__(256) void k_gemm(const u16* __restrict__ A, const u16* __restrict__ Wf,
                                              u16* __restrict__ C, int M){
    int wave = blockIdx.x*4 + (threadIdx.x>>6);
    int lane = threadIdx.x & 63;
    int rtiles = M >> 4;
    if (wave >= rtiles) return;
    int row0 = wave << 4;

    const u16* Arow = A + (size_t)(row0 + (lane&15))*HID + ((lane>>4)<<3);
    const bf16x8* Wp = reinterpret_cast<const bf16x8*>(Wf) + lane;

    f32x4 acc[8];
    #pragma unroll
    for (int j=0;j<8;++j) acc[j] = (f32x4){0.f,0.f,0.f,0.f};

    #pragma unroll
    for (int s=0;s<4;++s){
        bf16x8 a = *reinterpret_cast<const bf16x8*>(Arow + s*32);
        #pragma unroll
        for (int j=0;j<8;++j){
            bf16x8 b = Wp[(s*8 + j)*64];
            acc[j] = __builtin_amdgcn_mfma_f32_16x16x32_bf16(a, b, acc[j], 0, 0, 0);
        }
    }
    int r0 = row0 + ((lane>>4)<<2);
    int c0 = lane & 15;
    #pragma unroll
    for (int j=0;j<8;++j){
        #pragma unroll
        for (int r=0;r<4;++r){
            C[(size_t)(r0+r)*HID + j*16 + c0] = (u16)f2bfu(acc[j][r]);
        }
    }
}

// ---------- CSR-gather segment mean: one dest row per 16-lane group (4 rows/wave) ----------
// lane = g*16+c; group g owns dest row d = blk*16 + wave*4 + g; lane c covers cols [8c,8c+8) (16B).
// No cross-group reduction needed; epilogue fully utilized.
// MODE 0: out bf16, scale only | MODE 1: + bias + prelu | MODE 2: fp32 out, + bias + resid + prelu
template<int MODE>
__global__ __launch_bounds__(256) void k_agg(const u32* __restrict__ tab, const int* __restrict__ csr,
                                             const int* __restrict__ off, void* __restrict__ outp,
                                             const float* __restrict__ bias, const float* __restrict__ resid,
                                             const float* __restrict__ aptr, int nrows){
    int lane = threadIdx.x & 63;
    int g = lane >> 4, c = lane & 15;
    int d = blockIdx.x*16 + ((threadIdx.x>>6)<<2) + g;
    if (d >= nrows) return;
    int start = off[d], end = off[d+1];
    int deg = end - start;
    int gbase = g << 4;

    float a0=0.f,a1=0.f,a2=0.f,a3=0.f,a4=0.f,a5=0.f,a6=0.f,a7=0.f;
    for (int pos = start; pos < end; pos += 16){
        int myc = csr[pos + c];        // 16-entry window for this group (overread is masked below)
        int lim = end - pos;
        #pragma unroll
        for (int i=0;i<16;i+=4){
            int s0 = __shfl(myc, gbase|i,     64);
            int s1 = __shfl(myc, gbase|(i+1), 64);
            int s2 = __shfl(myc, gbase|(i+2), 64);
            int s3 = __shfl(myc, gbase|(i+3), 64);
            uint4 v0 = make_uint4(0u,0u,0u,0u), v1 = v0, v2 = v0, v3 = v0;
            if (i   < lim) v0 = *reinterpret_cast<const uint4*>(tab + (size_t)s0*64 + (c<<2));
            if (i+1 < lim) v1 = *reinterpret_cast<const uint4*>(tab + (size_t)s1*64 + (c<<2));
            if (i+2 < lim) v2 = *reinterpret_cast<const uint4*>(tab + (size_t)s2*64 + (c<<2));
            if (i+3 < lim) v3 = *reinterpret_cast<const uint4*>(tab + (size_t)s3*64 + (c<<2));
            a0 += blo(v0.x)+blo(v1.x)+blo(v2.x)+blo(v3.x);
            a1 += bhi(v0.x)+bhi(v1.x)+bhi(v2.x)+bhi(v3.x);
            a2 += blo(v0.y)+blo(v1.y)+blo(v2.y)+blo(v3.y);
            a3 += bhi(v0.y)+bhi(v1.y)+bhi(v2.y)+bhi(v3.y);
            a4 += blo(v0.z)+blo(v1.z)+blo(v2.z)+blo(v3.z);
            a5 += bhi(v0.z)+bhi(v1.z)+bhi(v2.z)+bhi(v3.z);
            a6 += blo(v0.w)+blo(v1.w)+blo(v2.w)+blo(v3.w);
            a7 += bhi(v0.w)+bhi(v1.w)+bhi(v2.w)+bhi(v3.w);
        }
    }
    float s = (deg > 0) ? 1.0f/(float)deg : 0.f;
    a0*=s; a1*=s; a2*=s; a3*=s; a4*=s; a5*=s; a6*=s; a7*=s;
    if constexpr (MODE >= 1){
        float4 b0 = *reinterpret_cast<const float4*>(bias + (c<<3));
        float4 b1v = *reinterpret_cast<const float4*>(bias + (c<<3) + 4);
        a0+=b0.x; a1+=b0.y; a2+=b0.z; a3+=b0.w;
        a4+=b1v.x; a5+=b1v.y; a6+=b1v.z; a7+=b1v.w;
    }
    if constexpr (MODE == 2){
        const float* rp = resid + (size_t)d*HID + (c<<3);
        float4 r0 = *reinterpret_cast<const float4*>(rp);
        float4 r1 = *reinterpret_cast<const float4*>(rp + 4);
        a0+=r0.x; a1+=r0.y; a2+=r0.z; a3+=r0.w;
        a4+=r1.x; a5+=r1.y; a6+=r1.z; a7+=r1.w;
    }
    if constexpr (MODE >= 1){
        float al = aptr[0];
        a0 = (a0>=0.f)? a0 : al*a0;  a1 = (a1>=0.f)? a1 : al*a1;
        a2 = (a2>=0.f)? a2 : al*a2;  a3 = (a3>=0.f)? a3 : al*a3;
        a4 = (a4>=0.f)? a4 : al*a4;  a5 = (a5>=0.f)? a5 : al*a5;
        a6 = (a6>=0.f)? a6 : al*a6;  a7 = (a7>=0.f)? a7 : al*a7;
    }
    if constexpr (MODE == 2){
        float* op = (float*)outp + (size_t)d*HID + (c<<3);
        *reinterpret_cast<float4*>(op)     = make_float4(a0,a1,a2,a3);
        *reinterpret_cast<float4*>(op + 4) = make_float4(a4,a5,a6,a7);
    } else {
        uint4 wv;
        wv.x = pk(a0,a1); wv.y = pk(a2,a3); wv.z = pk(a4,a5); wv.w = pk(a6,a7);
        *reinterpret_cast<uint4*>((u32*)outp + (size_t)d*64 + (c<<2)) = wv;
    }
}

extern "C" void kernel_launch(void* const* d_in, const int* in_sizes, int n_in,
                              void* d_out, int out_size, void* d_ws, size_t ws_size,
                              hipStream_t stream){
    (void)n_in; (void)out_size; (void)ws_size;
    const float* x  = (const float*)d_in[0];
    const int*  hei = (const int*)  d_in[1];
    const float* W1 = (const float*)d_in[2];
    const float* b1 = (const float*)d_in[3];
    const float* W2 = (const float*)d_in[4];
    const float* b2 = (const float*)d_in[5];
    const float* ap = (const float*)d_in[6];

    const int nN = in_sizes[0] / HID;   // 50000
    const int nE = in_sizes[1] / 2;     // 600000
    const int* nidx = hei;
    const int* eidx = hei + nE;
    const int nkeys = 2*nN;
    const int nb    = (nkeys + KPB - 1) / KPB;   // 391

    char* w = (char*)d_ws;
    size_t o = 0;
    auto alloc = [&](size_t bytes)->void*{
        void* p = (void*)(w + o);
        o += (bytes + 255) & ~(size_t)255;
        return p;
    };
    int* hist  = (int*)alloc((size_t)NBMAX*sizeof(int));
    int* bfill = (int*)alloc((size_t)NBMAX*sizeof(int));
    int* off   = (int*)alloc(((size_t)nkeys+1)*sizeof(int));
    int* csr   = (int*)alloc((size_t)2*nE*sizeof(int));
    u64* pairs = (u64*)alloc((size_t)2*nE*sizeof(u64));
    u16* hb    = (u16*)alloc((size_t)nN*HID*sizeof(u16));   // h bf16 (layer-1 output)
    u16* bufB  = (u16*)alloc((size_t)nN*HID*sizeof(u16));   // xw / hw
    u16* bufC  = (u16*)alloc((size_t)nN*HID*sizeof(u16));   // m / m2
    u16* w1f   = (u16*)alloc((size_t)HID*HID*sizeof(u16));
    u16* w2f   = (u16*)alloc((size_t)HID*HID*sizeof(u16));

    hipMemsetAsync(hist, 0, (size_t)2*NBMAX*sizeof(int), stream);   // hist + bfill (contiguous)

    const int pgrid  = (nE + IPB - 1)/IPB;       // 293
    const int rtiles = nN/16;                    // 3125
    const int ggrid  = (rtiles + 3)/4;           // 782

    // K1: hist ∪ wfrag
    k_hist_wfrag<<<pgrid + 128, 256, 0, stream>>>(nidx, eidx, hist, nE, nN, nb, pgrid, W1, W2, w1f, w2f);
    // K2: part ∪ layer-1 gemm (fp32 A)
    k_part_gemm<<<pgrid + ggrid, 256, 0, stream>>>(nidx, eidx, hist, bfill, pairs, nE, nN, nb, pgrid,
                                                   x, w1f, bufB, nN);
    // K3: bucket (also writes off sentinel)
    k_bucket<<<nb, 256, 0, stream>>>(pairs, hist, csr, off, nkeys, nb, 2*nE);

    const int agrid = (nN + 15)/16;              // 3125

    // layer 1
    k_agg<0><<<agrid, 256, 0, stream>>>((const u32*)bufB, csr, off + nN, bufC, nullptr, nullptr, nullptr, nN);
    k_agg<1><<<agrid, 256, 0, stream>>>((const u32*)bufC, csr, off,      hb,   b1, nullptr, ap, nN);
    // layer 2
    k_gemm<<<ggrid, 256, 0, stream>>>(hb, w2f, bufB, nN);
    k_agg<0><<<agrid, 256, 0, stream>>>((const u32*)bufB, csr, off + nN, bufC, nullptr, nullptr, nullptr, nN);
    k_agg<2><<<agrid, 256, 0, stream>>>((const u32*)bufC, csr, off, d_out, b2, x, ap, nN);
}

// Round 8
// 225.687 us; speedup vs baseline: 1.8564x; 1.0344x over previous
//
#include <hip/hip_runtime.h>

typedef unsigned short u16;
typedef unsigned int   u32;
typedef unsigned long long u64;

#define HID 128
#define KPB 256      // keys per coarse bucket (shift 8)
#define NBMAX 512    // max coarse buckets (actual: 391)
#define IPB 2048     // incidences per partition workgroup
#define CAP 6144     // LDS val-staging capacity per bucket (mean ~3070)
#define LSTRIDE 136  // LDS row stride (u16) for the fused h-tile: breaks pow-2 bank pattern

typedef __bf16 bf16x8 __attribute__((ext_vector_type(8)));
typedef float  f32x4  __attribute__((ext_vector_type(4)));

__device__ inline float u2f(u32 u){ union{u32 u;float f;} v; v.u=u; return v.f; }
__device__ inline u32   f2u(float f){ union{float f;u32 u;} v; v.f=f; return v.u; }
__device__ inline u32  f2bfu(float f){ u32 b=f2u(f); return ((b + 0x7FFFu + ((b>>16)&1u))>>16)&0xFFFFu; }
__device__ inline float blo(u32 u){ return u2f(u<<16); }
__device__ inline float bhi(u32 u){ return u2f(u & 0xFFFF0000u); }
__device__ inline u32  pk(float lo, float hi){ return (f2bfu(hi)<<16) | f2bfu(lo); }

// ---------- K1: coarse histogram (blocks [0,nhb)) ∪ W-fragment conversion (rest) ----------
__global__ __launch_bounds__(256) void k_hist_wfrag(const int* __restrict__ nidx, const int* __restrict__ eidx,
                                                    int* __restrict__ hist, int nE, int nN, int nb, int nhb,
                                                    const float* __restrict__ W1, const float* __restrict__ W2,
                                                    u16* __restrict__ W1f, u16* __restrict__ W2f){
    __shared__ int h[NBMAX];
    if ((int)blockIdx.x < nhb){
        for (int t=threadIdx.x; t<nb; t+=256) h[t]=0;
        __syncthreads();
        int base = blockIdx.x*IPB;
        for (int k=threadIdx.x; k<IPB; k+=256){
            int j = base+k;
            if (j < nE){
                atomicAdd(&h[nidx[j]>>8], 1);
                atomicAdd(&h[(nN+eidx[j])>>8], 1);
            }
        }
        __syncthreads();
        for (int t=threadIdx.x; t<nb; t+=256) if (h[t]) atomicAdd(&hist[t], h[t]);
    } else {
        int gid = ((int)blockIdx.x - nhb)*256 + threadIdx.x;   // 32768 total
        const float* W = (gid < 16384) ? W1 : W2;
        u16* Wf = (gid < 16384) ? W1f : W2f;
        int id = gid & 16383;
        int i = id & 7, l = (id>>3)&63, j = (id>>9)&7, s = id>>12;
        Wf[id] = (u16)f2bfu(W[(s*32 + ((l>>4)<<3) + i)*HID + (j<<4) + (l&15)]);
    }
}

// ---------- K2: partition into buckets (blocks [0,npb)) ∪ layer-1 GEMM fp32-A (rest) ----------
__global__ __launch_bounds__(256) void k_part_gemm(const int* __restrict__ nidx, const int* __restrict__ eidx,
                                                   const int* __restrict__ hist, int* __restrict__ bfill,
                                                   u64* __restrict__ pairs, int nE, int nN, int nb, int npb,
                                                   const float* __restrict__ A, const u16* __restrict__ Wf,
                                                   u16* __restrict__ C, int M){
    __shared__ int h[NBMAX], rsv[NBMAX], fl[NBMAX], bb[NBMAX], sd[256];
    int t = threadIdx.x;
    if ((int)blockIdx.x < npb){
        for (int i=t; i<nb; i+=256){ h[i]=0; fl[i]=0; }
        __syncthreads();
        int base = blockIdx.x*IPB;
        for (int k=t; k<IPB; k+=256){
            int j = base+k;
            if (j < nE){
                atomicAdd(&h[nidx[j]>>8], 1);
                atomicAdd(&h[(nN+eidx[j])>>8], 1);
            }
        }
        int c0 = (2*t   < nb) ? hist[2*t]   : 0;
        int c1 = (2*t+1 < nb) ? hist[2*t+1] : 0;
        int s = c0 + c1;
        sd[t] = s; __syncthreads();
        for (int o=1;o<256;o<<=1){ int u = (t>=o)? sd[t-o] : 0; __syncthreads(); sd[t]+=u; __syncthreads(); }
        int ex = sd[t] - s;
        if (2*t   < nb) bb[2*t]   = ex;
        if (2*t+1 < nb) bb[2*t+1] = ex + c0;
        __syncthreads();
        for (int i=t; i<nb; i+=256){ if (h[i]) rsv[i] = bb[i] + atomicAdd(&bfill[i], h[i]); }
        __syncthreads();
        for (int k=t; k<IPB; k+=256){
            int j = base+k;
            if (j < nE){
                int n = nidx[j], e = eidx[j];
                int b1 = n>>8;
                int p1 = rsv[b1] + atomicAdd(&fl[b1], 1);
                pairs[p1] = ((u64)(u32)n << 32) | (u32)e;
                int k2 = nN + e;
                int b2 = k2>>8;
                int p2 = rsv[b2] + atomicAdd(&fl[b2], 1);
                pairs[p2] = ((u64)(u32)k2 << 32) | (u32)n;
            }
        }
    } else {
        int wave = ((int)blockIdx.x - npb)*4 + (t>>6);
        int lane = t & 63;
        int rtiles = M >> 4;
        if (wave >= rtiles) return;
        int row0 = wave << 4;
        const float* Arow = A + (size_t)(row0 + (lane&15))*HID + ((lane>>4)<<3);
        const bf16x8* Wp = reinterpret_cast<const bf16x8*>(Wf) + lane;
        f32x4 acc[8];
        #pragma unroll
        for (int j=0;j<8;++j) acc[j] = (f32x4){0.f,0.f,0.f,0.f};
        #pragma unroll
        for (int s=0;s<4;++s){
            float4 f0 = *reinterpret_cast<const float4*>(Arow + s*32);
            float4 f1 = *reinterpret_cast<const float4*>(Arow + s*32 + 4);
            union { u16 h[8]; bf16x8 v; } au;
            au.h[0]=(u16)f2bfu(f0.x); au.h[1]=(u16)f2bfu(f0.y); au.h[2]=(u16)f2bfu(f0.z); au.h[3]=(u16)f2bfu(f0.w);
            au.h[4]=(u16)f2bfu(f1.x); au.h[5]=(u16)f2bfu(f1.y); au.h[6]=(u16)f2bfu(f1.z); au.h[7]=(u16)f2bfu(f1.w);
            #pragma unroll
            for (int j=0;j<8;++j){
                bf16x8 b = Wp[(s*8 + j)*64];
                acc[j] = __builtin_amdgcn_mfma_f32_16x16x32_bf16(au.v, b, acc[j], 0, 0, 0);
            }
        }
        int r0 = row0 + ((lane>>4)<<2);
        int c0 = lane & 15;
        #pragma unroll
        for (int j=0;j<8;++j){
            #pragma unroll
            for (int r=0;r<4;++r){
                C[(size_t)(r0+r)*HID + j*16 + c0] = (u16)f2bfu(acc[j][r]);
            }
        }
    }
}

// ---------- per-bucket fine counting sort in LDS (computes own base locally) ----------
__global__ __launch_bounds__(256) void k_bucket(const u64* __restrict__ pairs, const int* __restrict__ hist,
                                                int* __restrict__ csr, int* __restrict__ off,
                                                int nkeys, int nb, int total){
    __shared__ int cntS[KPB];
    __shared__ int fillS[KPB];
    __shared__ int bbS[NBMAX+1];
    __shared__ int sd[256];
    __shared__ int vals[CAP];
    int b = blockIdx.x;
    int t = threadIdx.x;
    if (b == 0 && t == 0) off[nkeys] = total;
    int c0 = (2*t   < nb) ? hist[2*t]   : 0;
    int c1 = (2*t+1 < nb) ? hist[2*t+1] : 0;
    int s = c0 + c1;
    sd[t] = s; __syncthreads();
    for (int o=1;o<256;o<<=1){ int u = (t>=o)? sd[t-o] : 0; __syncthreads(); sd[t]+=u; __syncthreads(); }
    int ex = sd[t] - s;
    if (2*t   <= nb) bbS[2*t]   = ex;
    if (2*t+1 <= nb) bbS[2*t+1] = ex + c0;
    __syncthreads();
    int base = bbS[b];
    int n = bbS[b+1] - base;
    int k0 = b * KPB;

    cntS[t] = 0;
    __syncthreads();
    for (int i=t; i<n; i+=256){
        u64 p = pairs[base+i];
        atomicAdd(&cntS[(int)(p>>32) - k0], 1);
    }
    __syncthreads();
    int c = cntS[t];
    __syncthreads();
    fillS[t] = c; __syncthreads();
    for (int o=1;o<256;o<<=1){ int u = (t>=o)? fillS[t-o] : 0; __syncthreads(); fillS[t]+=u; __syncthreads(); }
    int ex2 = fillS[t] - c;
    __syncthreads();
    fillS[t] = ex2;
    __syncthreads();
    int k = k0 + t;
    if (k < nkeys) off[k] = base + ex2;
    bool fits = (n <= CAP);
    for (int i=t; i<n; i+=256){
        u64 p = pairs[base+i];
        int kl = (int)(p>>32) - k0;
        int pos = atomicAdd(&fillS[kl], 1);
        if (fits) vals[pos] = (int)(u32)p;
        else      csr[base+pos] = (int)(u32)p;
    }
    __syncthreads();
    if (fits){
        for (int i=t; i<n; i+=256) csr[base+i] = vals[i];
    }
}

// ---------- CSR-gather segment mean: one dest row per 16-lane group (4 rows/wave) ----------
// MODE 0: out bf16, scale only | MODE 2: fp32 out, + bias + resid + prelu
template<int MODE>
__global__ __launch_bounds__(256) void k_agg(const u32* __restrict__ tab, const int* __restrict__ csr,
                                             const int* __restrict__ off, void* __restrict__ outp,
                                             const float* __restrict__ bias, const float* __restrict__ resid,
                                             const float* __restrict__ aptr, int nrows){
    int lane = threadIdx.x & 63;
    int g = lane >> 4, c = lane & 15;
    int d = blockIdx.x*16 + ((threadIdx.x>>6)<<2) + g;
    if (d >= nrows) return;
    int start = off[d], end = off[d+1];
    int deg = end - start;
    int gbase = g << 4;

    float a0=0.f,a1=0.f,a2=0.f,a3=0.f,a4=0.f,a5=0.f,a6=0.f,a7=0.f;
    for (int pos = start; pos < end; pos += 16){
        int myc = csr[pos + c];
        int lim = end - pos;
        #pragma unroll
        for (int i=0;i<16;i+=4){
            int s0 = __shfl(myc, gbase|i,     64);
            int s1 = __shfl(myc, gbase|(i+1), 64);
            int s2 = __shfl(myc, gbase|(i+2), 64);
            int s3 = __shfl(myc, gbase|(i+3), 64);
            uint4 v0 = make_uint4(0u,0u,0u,0u), v1 = v0, v2 = v0, v3 = v0;
            if (i   < lim) v0 = *reinterpret_cast<const uint4*>(tab + (size_t)s0*64 + (c<<2));
            if (i+1 < lim) v1 = *reinterpret_cast<const uint4*>(tab + (size_t)s1*64 + (c<<2));
            if (i+2 < lim) v2 = *reinterpret_cast<const uint4*>(tab + (size_t)s2*64 + (c<<2));
            if (i+3 < lim) v3 = *reinterpret_cast<const uint4*>(tab + (size_t)s3*64 + (c<<2));
            a0 += blo(v0.x)+blo(v1.x)+blo(v2.x)+blo(v3.x);
            a1 += bhi(v0.x)+bhi(v1.x)+bhi(v2.x)+bhi(v3.x);
            a2 += blo(v0.y)+blo(v1.y)+blo(v2.y)+blo(v3.y);
            a3 += bhi(v0.y)+bhi(v1.y)+bhi(v2.y)+bhi(v3.y);
            a4 += blo(v0.z)+blo(v1.z)+blo(v2.z)+blo(v3.z);
            a5 += bhi(v0.z)+bhi(v1.z)+bhi(v2.z)+bhi(v3.z);
            a6 += blo(v0.w)+blo(v1.w)+blo(v2.w)+blo(v3.w);
            a7 += bhi(v0.w)+bhi(v1.w)+bhi(v2.w)+bhi(v3.w);
        }
    }
    float s = (deg > 0) ? 1.0f/(float)deg : 0.f;
    a0*=s; a1*=s; a2*=s; a3*=s; a4*=s; a5*=s; a6*=s; a7*=s;
    if constexpr (MODE == 2){
        float4 b0 = *reinterpret_cast<const float4*>(bias + (c<<3));
        float4 b1v = *reinterpret_cast<const float4*>(bias + (c<<3) + 4);
        a0+=b0.x; a1+=b0.y; a2+=b0.z; a3+=b0.w;
        a4+=b1v.x; a5+=b1v.y; a6+=b1v.z; a7+=b1v.w;
        const float* rp = resid + (size_t)d*HID + (c<<3);
        float4 r0 = *reinterpret_cast<const float4*>(rp);
        float4 r1 = *reinterpret_cast<const float4*>(rp + 4);
        a0+=r0.x; a1+=r0.y; a2+=r0.z; a3+=r0.w;
        a4+=r1.x; a5+=r1.y; a6+=r1.z; a7+=r1.w;
        float al = aptr[0];
        a0 = (a0>=0.f)? a0 : al*a0;  a1 = (a1>=0.f)? a1 : al*a1;
        a2 = (a2>=0.f)? a2 : al*a2;  a3 = (a3>=0.f)? a3 : al*a3;
        a4 = (a4>=0.f)? a4 : al*a4;  a5 = (a5>=0.f)? a5 : al*a5;
        a6 = (a6>=0.f)? a6 : al*a6;  a7 = (a7>=0.f)? a7 : al*a7;
        float* op = (float*)outp + (size_t)d*HID + (c<<3);
        *reinterpret_cast<float4*>(op)     = make_float4(a0,a1,a2,a3);
        *reinterpret_cast<float4*>(op + 4) = make_float4(a4,a5,a6,a7);
    } else {
        uint4 wv;
        wv.x = pk(a0,a1); wv.y = pk(a2,a3); wv.z = pk(a4,a5); wv.w = pk(a6,a7);
        *reinterpret_cast<uint4*>((u32*)outp + (size_t)d*64 + (c<<2)) = wv;
    }
}

// ---------- FUSED: agg MODE-1 (gather + scale + bias + prelu -> 16x128 h-tile in LDS)
//            + 16x128 @ 128x128 MFMA GEMM (each wave: 2 column tiles) -> C = h @ W2 ----------
__global__ __launch_bounds__(256) void k_agg1_gemm(const u32* __restrict__ tab, const int* __restrict__ csr,
                                                   const int* __restrict__ off, u16* __restrict__ C,
                                                   const float* __restrict__ bias, const float* __restrict__ aptr,
                                                   const u16* __restrict__ Wf, int nrows){
    __shared__ u16 hS[16*LSTRIDE];
    int t = threadIdx.x;
    int lane = t & 63;
    int wv = t >> 6;
    int g = lane >> 4, c = lane & 15;
    int r = (wv<<2) + g;              // local row 0..15
    int d = blockIdx.x*16 + r;
    int gbase = g << 4;

    float a0=0.f,a1=0.f,a2=0.f,a3=0.f,a4=0.f,a5=0.f,a6=0.f,a7=0.f;
    if (d < nrows){
        int start = off[d], end = off[d+1];
        int deg = end - start;
        for (int pos = start; pos < end; pos += 16){
            int myc = csr[pos + c];
            int lim = end - pos;
            #pragma unroll
            for (int i=0;i<16;i+=4){
                int s0 = __shfl(myc, gbase|i,     64);
                int s1 = __shfl(myc, gbase|(i+1), 64);
                int s2 = __shfl(myc, gbase|(i+2), 64);
                int s3 = __shfl(myc, gbase|(i+3), 64);
                uint4 v0 = make_uint4(0u,0u,0u,0u), v1 = v0, v2 = v0, v3 = v0;
                if (i   < lim) v0 = *reinterpret_cast<const uint4*>(tab + (size_t)s0*64 + (c<<2));
                if (i+1 < lim) v1 = *reinterpret_cast<const uint4*>(tab + (size_t)s1*64 + (c<<2));
                if (i+2 < lim) v2 = *reinterpret_cast<const uint4*>(tab + (size_t)s2*64 + (c<<2));
                if (i+3 < lim) v3 = *reinterpret_cast<const uint4*>(tab + (size_t)s3*64 + (c<<2));
                a0 += blo(v0.x)+blo(v1.x)+blo(v2.x)+blo(v3.x);
                a1 += bhi(v0.x)+bhi(v1.x)+bhi(v2.x)+bhi(v3.x);
                a2 += blo(v0.y)+blo(v1.y)+blo(v2.y)+blo(v3.y);
                a3 += bhi(v0.y)+bhi(v1.y)+bhi(v2.y)+bhi(v3.y);
                a4 += blo(v0.z)+blo(v1.z)+blo(v2.z)+blo(v3.z);
                a5 += bhi(v0.z)+bhi(v1.z)+bhi(v2.z)+bhi(v3.z);
                a6 += blo(v0.w)+blo(v1.w)+blo(v2.w)+blo(v3.w);
                a7 += bhi(v0.w)+bhi(v1.w)+bhi(v2.w)+bhi(v3.w);
            }
        }
        float s = (deg > 0) ? 1.0f/(float)deg : 0.f;
        a0*=s; a1*=s; a2*=s; a3*=s; a4*=s; a5*=s; a6*=s; a7*=s;
        float4 b0 = *reinterpret_cast<const float4*>(bias + (c<<3));
        float4 b1v = *reinterpret_cast<const float4*>(bias + (c<<3) + 4);
        a0+=b0.x; a1+=b0.y; a2+=b0.z; a3+=b0.w;
        a4+=b1v.x; a5+=b1v.y; a6+=b1v.z; a7+=b1v.w;
        float al = aptr[0];
        a0 = (a0>=0.f)? a0 : al*a0;  a1 = (a1>=0.f)? a1 : al*a1;
        a2 = (a2>=0.f)? a2 : al*a2;  a3 = (a3>=0.f)? a3 : al*a3;
        a4 = (a4>=0.f)? a4 : al*a4;  a5 = (a5>=0.f)? a5 : al*a5;
        a6 = (a6>=0.f)? a6 : al*a6;  a7 = (a7>=0.f)? a7 : al*a7;
    }
    // stage h row (bf16) into LDS
    {
        uint4 wv4;
        wv4.x = pk(a0,a1); wv4.y = pk(a2,a3); wv4.z = pk(a4,a5); wv4.w = pk(a6,a7);
        *reinterpret_cast<uint4*>((u32*)(hS + (size_t)r*LSTRIDE) + (c<<2)) = wv4;
    }
    __syncthreads();

    // MFMA: wave wv computes column tiles j = 2*wv, 2*wv+1 of C[block rows] = h @ W2
    const u16* Arow = hS + (size_t)(lane&15)*LSTRIDE + ((lane>>4)<<3);
    const bf16x8* Wp = reinterpret_cast<const bf16x8*>(Wf) + lane;
    f32x4 acc0 = (f32x4){0.f,0.f,0.f,0.f}, acc1 = acc0;
    #pragma unroll
    for (int s=0;s<4;++s){
        bf16x8 a = *reinterpret_cast<const bf16x8*>(Arow + s*32);
        bf16x8 bA = Wp[(s*8 + 2*wv    )*64];
        bf16x8 bB = Wp[(s*8 + 2*wv + 1)*64];
        acc0 = __builtin_amdgcn_mfma_f32_16x16x32_bf16(a, bA, acc0, 0, 0, 0);
        acc1 = __builtin_amdgcn_mfma_f32_16x16x32_bf16(a, bB, acc1, 0, 0, 0);
    }
    int r0 = (lane>>4)<<2;
    int c0 = lane & 15;
    #pragma unroll
    for (int rr=0;rr<4;++rr){
        int row = blockIdx.x*16 + r0 + rr;
        if (row < nrows){
            C[(size_t)row*HID + (2*wv  )*16 + c0] = (u16)f2bfu(acc0[rr]);
            C[(size_t)row*HID + (2*wv+1)*16 + c0] = (u16)f2bfu(acc1[rr]);
        }
    }
}

extern "C" void kernel_launch(void* const* d_in, const int* in_sizes, int n_in,
                              void* d_out, int out_size, void* d_ws, size_t ws_size,
                              hipStream_t stream){
    (void)n_in; (void)out_size; (void)ws_size;
    const float* x  = (const float*)d_in[0];
    const int*  hei = (const int*)  d_in[1];
    const float* W1 = (const float*)d_in[2];
    const float* b1 = (const float*)d_in[3];
    const float* W2 = (const float*)d_in[4];
    const float* b2 = (const float*)d_in[5];
    const float* ap = (const float*)d_in[6];

    const int nN = in_sizes[0] / HID;   // 50000
    const int nE = in_sizes[1] / 2;     // 600000
    const int* nidx = hei;
    const int* eidx = hei + nE;
    const int nkeys = 2*nN;
    const int nb    = (nkeys + KPB - 1) / KPB;   // 391

    char* w = (char*)d_ws;
    size_t o = 0;
    auto alloc = [&](size_t bytes)->void*{
        void* p = (void*)(w + o);
        o += (bytes + 255) & ~(size_t)255;
        return p;
    };
    int* hist  = (int*)alloc((size_t)NBMAX*sizeof(int));
    int* bfill = (int*)alloc((size_t)NBMAX*sizeof(int));
    int* off   = (int*)alloc(((size_t)nkeys+1)*sizeof(int));
    int* csr   = (int*)alloc((size_t)2*nE*sizeof(int));
    u64* pairs = (u64*)alloc((size_t)2*nE*sizeof(u64));
    u16* bufB  = (u16*)alloc((size_t)nN*HID*sizeof(u16));   // xw / hw
    u16* bufC  = (u16*)alloc((size_t)nN*HID*sizeof(u16));   // m / m2
    u16* w1f   = (u16*)alloc((size_t)HID*HID*sizeof(u16));
    u16* w2f   = (u16*)alloc((size_t)HID*HID*sizeof(u16));

    hipMemsetAsync(hist, 0, (size_t)2*NBMAX*sizeof(int), stream);   // hist + bfill (contiguous)

    const int pgrid  = (nE + IPB - 1)/IPB;       // 293
    const int rtiles = nN/16;                    // 3125
    const int ggrid  = (rtiles + 3)/4;           // 782

    // K1: hist ∪ wfrag
    k_hist_wfrag<<<pgrid + 128, 256, 0, stream>>>(nidx, eidx, hist, nE, nN, nb, pgrid, W1, W2, w1f, w2f);
    // K2: part ∪ layer-1 gemm (fp32 A)
    k_part_gemm<<<pgrid + ggrid, 256, 0, stream>>>(nidx, eidx, hist, bfill, pairs, nE, nN, nb, pgrid,
                                                   x, w1f, bufB, nN);
    // K3: bucket (also writes off sentinel)
    k_bucket<<<nb, 256, 0, stream>>>(pairs, hist, csr, off, nkeys, nb, 2*nE);

    const int agrid = (nN + 15)/16;              // 3125

    // layer 1
    k_agg<0><<<agrid, 256, 0, stream>>>((const u32*)bufB, csr, off + nN, bufC, nullptr, nullptr, nullptr, nN);
    // fused: agg MODE-1 (h) + h @ W2 -> bufB
    k_agg1_gemm<<<agrid, 256, 0, stream>>>((const u32*)bufC, csr, off, bufB, b1, ap, w2f, nN);
    // layer 2
    k_agg<0><<<agrid, 256, 0, stream>>>((const u32*)bufB, csr, off + nN, bufC, nullptr, nullptr, nullptr, nN);
    k_agg<2><<<agrid, 256, 0, stream>>>((const u32*)bufC, csr, off, d_out, b2, x, ap, nN);
}